// Round 23
// baseline (636.260 us; speedup 1.0000x reference)
//
#include <hip/hip_runtime.h>
#include <hip/hip_bf16.h>

#define DM 256
#define NH 8
#define DK 32
#define BSZ 2
#define SEQ 2048
#define ROWS (BSZ*SEQ)   // 4096
#define RT 16            // query rows per attention tile (full MFMA rows)
#define SRB 2312         // ushort row stride; swizzle phys = j + 8*(j>>6), max 2295

static __device__ __forceinline__ int sw8(int j) { return j + ((j >> 6) << 3); }

typedef __attribute__((ext_vector_type(8))) short short8;
typedef __attribute__((ext_vector_type(4))) float f32x4;

// f32 -> bf16 bits, round-to-nearest-even (validated r15)
static __device__ __forceinline__ unsigned short f2bf(float f) {
    unsigned u = __float_as_uint(f);
    return (unsigned short)((u + 0x7FFFu + ((u >> 16) & 1u)) >> 16);
}
static __device__ __forceinline__ float bf2f(unsigned short h) {
    return __uint_as_float(((unsigned)h) << 16);
}

#define MFMA_BF16 __builtin_amdgcn_mfma_f32_16x16x32_bf16
#define LOG2E 1.44269504088896340736f

// ---------- reduction helpers ----------
static __device__ __forceinline__ float waveRedSum(float v) {
    #pragma unroll
    for (int off = 32; off > 0; off >>= 1) v += __shfl_down(v, off, 64);
    return v;
}

// ---------- one-time: weights -> split-bf16, transposed [n][k] ----------
__global__ __launch_bounds__(256) void convert_w_kernel(
    const float* __restrict__ S0, const float* __restrict__ S1, const float* __restrict__ S2,
    const float* __restrict__ S3, const float* __restrict__ S4, const float* __restrict__ S5,
    const float* __restrict__ S6, const float* __restrict__ S7, const float* __restrict__ S8,
    unsigned short* __restrict__ dst)
{
    const float* W;
    int s = blockIdx.y;
    if (s == 0) W = S0; else if (s == 1) W = S1; else if (s == 2) W = S2;
    else if (s == 3) W = S3; else if (s == 4) W = S4; else if (s == 5) W = S5;
    else if (s == 6) W = S6; else if (s == 7) W = S7; else W = S8;
    unsigned short* H = dst + (size_t)s * 131072;
    unsigned short* L = H + 65536;

    int e = blockIdx.x * 1024 + threadIdx.x * 4;
    int k = e >> 8, n = e & 255;
    float4 w4 = *(const float4*)(W + e);
    float v[4] = {w4.x, w4.y, w4.z, w4.w};
    #pragma unroll
    for (int i = 0; i < 4; ++i) {
        unsigned short h = f2bf(v[i]);
        H[(size_t)(n + i) * 256 + k] = h;
        L[(size_t)(n + i) * 256 + k] = (unsigned short)f2bf(v[i] - bf2f(h));
    }
}

// ---------- batched MFMA GEMM (16x256/block, 4 sets) with optional ----------
// split-bf16 side outputs: KSo = [row][col] hi/lo; VSo = [col][row] hi/lo.
__global__ __launch_bounds__(256) void gemm4_kernel(
    const float* __restrict__ X0, const unsigned short* __restrict__ H0, const float* __restrict__ B0,
    float* __restrict__ Y0, unsigned short* __restrict__ K0o, unsigned short* __restrict__ V0o,
    const float* __restrict__ X1, const unsigned short* __restrict__ H1, const float* __restrict__ B1,
    float* __restrict__ Y1, unsigned short* __restrict__ K1o, unsigned short* __restrict__ V1o,
    const float* __restrict__ X2, const unsigned short* __restrict__ H2, const float* __restrict__ B2,
    float* __restrict__ Y2, unsigned short* __restrict__ K2o, unsigned short* __restrict__ V2o,
    const float* __restrict__ X3, const unsigned short* __restrict__ H3, const float* __restrict__ B3,
    float* __restrict__ Y3, unsigned short* __restrict__ K3o, unsigned short* __restrict__ V3o)
{
    const float *X, *Bias; const unsigned short* H; float* Yf;
    unsigned short *KSo, *VSo;
    int s = blockIdx.y;
    if (s == 0)      { X = X0; H = H0; Bias = B0; Yf = Y0; KSo = K0o; VSo = V0o; }
    else if (s == 1) { X = X1; H = H1; Bias = B1; Yf = Y1; KSo = K1o; VSo = V1o; }
    else if (s == 2) { X = X2; H = H2; Bias = B2; Yf = Y2; KSo = K2o; VSo = V2o; }
    else             { X = X3; H = H3; Bias = B3; Yf = Y3; KSo = K3o; VSo = V3o; }
    const unsigned short* L = H + 65536;

    __shared__ __align__(16) unsigned short XhL[16 * 264];
    __shared__ __align__(16) unsigned short XlL[16 * 264];
    int t = threadIdx.x;
    int r0 = blockIdx.x * 16;
    {   // stage X tile as split bf16
        int r = t >> 4, c0 = (t & 15) * 16;
        const float* xp = X + (size_t)(r0 + r) * DM + c0;
        #pragma unroll
        for (int i = 0; i < 16; i += 4) {
            float4 v4 = *(const float4*)(xp + i);
            float vv[4] = {v4.x, v4.y, v4.z, v4.w};
            #pragma unroll
            for (int j = 0; j < 4; ++j) {
                unsigned short h = f2bf(vv[j]);
                XhL[r * 264 + c0 + i + j] = h;
                XlL[r * 264 + c0 + i + j] = (unsigned short)f2bf(vv[j] - bf2f(h));
            }
        }
    }
    __syncthreads();
    int lane = t & 63, wv = t >> 6;
    int m = lane & 15, quad = lane >> 4;
    f32x4 aa[4];
    #pragma unroll
    for (int nt = 0; nt < 4; ++nt) { aa[nt][0]=0.f; aa[nt][1]=0.f; aa[nt][2]=0.f; aa[nt][3]=0.f; }
    #pragma unroll 1
    for (int kc = 0; kc < 8; ++kc) {
        int k0 = kc * 32;
        short8 Ah = *(const short8*)&XhL[m * 264 + k0 + quad * 8];
        short8 Al = *(const short8*)&XlL[m * 264 + k0 + quad * 8];
        size_t boff = (size_t)(wv * 64 + m) * 256 + k0 + quad * 8;
        #pragma unroll
        for (int nt = 0; nt < 4; ++nt) {
            short8 Bh = *(const short8*)(H + boff + nt * 16 * 256);
            short8 Bl = *(const short8*)(L + boff + nt * 16 * 256);
            aa[nt] = MFMA_BF16(Al, Bh, aa[nt], 0, 0, 0);
            aa[nt] = MFMA_BF16(Ah, Bl, aa[nt], 0, 0, 0);
            aa[nt] = MFMA_BF16(Ah, Bh, aa[nt], 0, 0, 0);
        }
    }
    // epilogue: D col = lane&15 (+16*nt +64*wv), row = quad*4+g
    int col0 = wv * 64 + m;
    #pragma unroll
    for (int nt = 0; nt < 4; ++nt) {
        int col = col0 + nt * 16;
        float bb = Bias[col];
        float yv[4];
        #pragma unroll
        for (int g = 0; g < 4; ++g) yv[g] = aa[nt][g] + bb;
        if (Yf) {
            #pragma unroll
            for (int g = 0; g < 4; ++g)
                Yf[(size_t)(r0 + quad * 4 + g) * DM + col] = yv[g];
        }
        if (KSo) {
            unsigned short* KH = KSo;
            unsigned short* KL = KSo + (size_t)ROWS * DM;
            #pragma unroll
            for (int g = 0; g < 4; ++g) {
                unsigned short hb = f2bf(yv[g]);
                KH[(size_t)(r0 + quad * 4 + g) * DM + col] = hb;
                KL[(size_t)(r0 + quad * 4 + g) * DM + col] =
                    (unsigned short)f2bf(yv[g] - bf2f(hb));
            }
        }
        if (VSo) {
            unsigned short* VH = VSo;
            unsigned short* VL = VSo + (size_t)ROWS * DM;
            ushort4 h4, l4;
            unsigned short hb;
            hb = f2bf(yv[0]); h4.x = hb; l4.x = (unsigned short)f2bf(yv[0] - bf2f(hb));
            hb = f2bf(yv[1]); h4.y = hb; l4.y = (unsigned short)f2bf(yv[1] - bf2f(hb));
            hb = f2bf(yv[2]); h4.z = hb; l4.z = (unsigned short)f2bf(yv[2] - bf2f(hb));
            hb = f2bf(yv[3]); h4.w = hb; l4.w = (unsigned short)f2bf(yv[3] - bf2f(hb));
            *(ushort4*)&VH[(size_t)col * ROWS + r0 + quad * 4] = h4;
            *(ushort4*)&VL[(size_t)col * ROWS + r0 + quad * 4] = l4;
        }
    }
}

// ---------- MFMA GEMM + residual + LayerNorm fused (2 sets) ----------
__global__ __launch_bounds__(256) void gemm_ln2_kernel(
    const float* __restrict__ X0, const unsigned short* __restrict__ H0, const float* __restrict__ B0,
    const float* __restrict__ R0, const float* __restrict__ G0, const float* __restrict__ L0,
    float* __restrict__ Y0, int bc0,
    const float* __restrict__ X1, const unsigned short* __restrict__ H1, const float* __restrict__ B1,
    const float* __restrict__ R1, const float* __restrict__ G1, const float* __restrict__ L1,
    float* __restrict__ Y1, int bc1)
{
    const float *X, *Bias, *R, *G, *Lb; const unsigned short* H; float* Y; int bc;
    if (blockIdx.y == 0) { X=X0; H=H0; Bias=B0; R=R0; G=G0; Lb=L0; Y=Y0; bc=bc0; }
    else                 { X=X1; H=H1; Bias=B1; R=R1; G=G1; Lb=L1; Y=Y1; bc=bc1; }
    const unsigned short* L = H + 65536;

    __shared__ __align__(16) unsigned short XhL[16 * 264];
    __shared__ __align__(16) unsigned short XlL[16 * 264];
    __shared__ __align__(16) float yl[16 * 260];
    int t = threadIdx.x;
    int r0 = blockIdx.x * 16;
    {   int r = t >> 4, c0 = (t & 15) * 16;
        const float* xp = X + (size_t)(r0 + r) * DM + c0;
        #pragma unroll
        for (int i = 0; i < 16; i += 4) {
            float4 v4 = *(const float4*)(xp + i);
            float vv[4] = {v4.x, v4.y, v4.z, v4.w};
            #pragma unroll
            for (int j = 0; j < 4; ++j) {
                unsigned short h = f2bf(vv[j]);
                XhL[r * 264 + c0 + i + j] = h;
                XlL[r * 264 + c0 + i + j] = (unsigned short)f2bf(vv[j] - bf2f(h));
            }
        }
    }
    __syncthreads();
    int lane = t & 63, wv = t >> 6;
    int m = lane & 15, quad = lane >> 4;
    f32x4 aa[4];
    #pragma unroll
    for (int nt = 0; nt < 4; ++nt) { aa[nt][0]=0.f; aa[nt][1]=0.f; aa[nt][2]=0.f; aa[nt][3]=0.f; }
    #pragma unroll 1
    for (int kc = 0; kc < 8; ++kc) {
        int k0 = kc * 32;
        short8 Ah = *(const short8*)&XhL[m * 264 + k0 + quad * 8];
        short8 Al = *(const short8*)&XlL[m * 264 + k0 + quad * 8];
        size_t boff = (size_t)(wv * 64 + m) * 256 + k0 + quad * 8;
        #pragma unroll
        for (int nt = 0; nt < 4; ++nt) {
            short8 Bh = *(const short8*)(H + boff + nt * 16 * 256);
            short8 Bl = *(const short8*)(L + boff + nt * 16 * 256);
            aa[nt] = MFMA_BF16(Al, Bh, aa[nt], 0, 0, 0);
            aa[nt] = MFMA_BF16(Ah, Bl, aa[nt], 0, 0, 0);
            aa[nt] = MFMA_BF16(Ah, Bh, aa[nt], 0, 0, 0);
        }
    }
    {
        int col0 = wv * 64 + m;
        #pragma unroll
        for (int nt = 0; nt < 4; ++nt) {
            int col = col0 + nt * 16;
            float bb = Bias[col];
            #pragma unroll
            for (int g = 0; g < 4; ++g) {
                int row = quad * 4 + g;
                float res = bc ? R[col] : R[(size_t)(r0 + row) * DM + col];
                yl[row * 260 + col] = aa[nt][g] + bb + res;
            }
        }
    }
    __syncthreads();
    {
        int r = t >> 4, c0 = (t & 15) * 16;
        float vals[16];
        float part = 0.f;
        #pragma unroll
        for (int i = 0; i < 16; ++i) { vals[i] = yl[r * 260 + c0 + i]; part += vals[i]; }
        #pragma unroll
        for (int off = 8; off; off >>= 1) part += __shfl_xor(part, off, 16);
        float mean = part * (1.f / DM);
        float vp = 0.f;
        #pragma unroll
        for (int i = 0; i < 16; ++i) { float d = vals[i] - mean; vp += d * d; }
        #pragma unroll
        for (int off = 8; off; off >>= 1) vp += __shfl_xor(vp, off, 16);
        float rs = rsqrtf(vp * (1.f / DM) + 1e-5f);
        float* yp = Y + (size_t)(r0 + r) * DM + c0;
        #pragma unroll
        for (int i = 0; i < 16; i += 4) {
            float4 o;
            o.x = (vals[i+0] - mean) * rs * G[c0+i+0] + Lb[c0+i+0];
            o.y = (vals[i+1] - mean) * rs * G[c0+i+1] + Lb[c0+i+1];
            o.z = (vals[i+2] - mean) * rs * G[c0+i+2] + Lb[c0+i+2];
            o.w = (vals[i+3] - mean) * rs * G[c0+i+3] + Lb[c0+i+3];
            *(float4*)(yp + i) = o;
        }
    }
}

// ---------- tiled attention with distance-decay bias ----------
// RT=16 + 512 threads (r22). Phase 1 and phase 5 process TWO chunks per
// wave-iteration with independent accumulators (ILP x2 — MfmaUtil was 3.3%,
// MFMAs never back-to-back). Pass C: upper eff clamp dropped (never binds),
// per-chunk float pos base.
__global__ __launch_bounds__(512) void attn_tile_kernel(
    const float* __restrict__ Q0, const float* __restrict__ Kf0,
    const unsigned short* __restrict__ KS0, const unsigned short* __restrict__ VS0,
    const float* __restrict__ g0, float* __restrict__ O0,
    const float* __restrict__ Q1, const float* __restrict__ Kf1,
    const unsigned short* __restrict__ KS1, const unsigned short* __restrict__ VS1,
    const float* __restrict__ g1, float* __restrict__ O1,
    int peek, int qbcast)
{
    __shared__ __align__(16) unsigned short SB[RT * SRB];
    __shared__ float qs[RT][DK];
    __shared__ float l2inv_s[RT];

    int y = blockIdx.y;
    int set = y >> 4, bh = y & 15;
    const float* Q = set ? Q1 : Q0;
    const float* Kf = set ? Kf1 : Kf0;
    const unsigned short* KS = set ? KS1 : KS0;
    const unsigned short* VS = set ? VS1 : VS0;
    const float* gm = set ? g1 : g0;
    float* O = set ? O1 : O0;

    int b = bh >> 3, h = bh & 7;
    int i0 = ((int)gridDim.x - 1 - (int)blockIdx.x) * RT;   // largest-first
    int t = threadIdx.x;
    size_t base = ((size_t)b * SEQ) * DM + (size_t)h * DK;

    {   // load Q tile (512 threads = 16 rows x 32)
        int r = t >> 5, d = t & 31;
        qs[r][d] = qbcast ? Q[(size_t)h * DK + d]
                          : Q[base + (size_t)(i0 + r) * DM + d];
    }
    __syncthreads();

    int njAll = peek ? (i0 + RT) : (i0 + RT - 1);  // >= 15 always
    int njPad32 = (njAll + 31) & ~31;
    int njPad128 = (njAll + 127) & ~127;           // pass-C read extent
    const float scaleL2 = 0.17677669529663687f * LOG2E;   // 1/sqrt(32)*log2e

    // ---- Phase 1: scores (log2-domain bf16 into SB).
    if (qbcast) {
        #pragma unroll 1
        for (int jb = t; jb < njAll; jb += 2048) {
            int j1 = jb + 512, j2 = jb + 1024, j3 = jb + 1536;
            int c1 = j1 < njAll ? j1 : jb;
            int c2 = j2 < njAll ? j2 : jb;
            int c3 = j3 < njAll ? j3 : jb;
            const float4* kp0 = (const float4*)(Kf + base + (size_t)jb * DM);
            const float4* kp1 = (const float4*)(Kf + base + (size_t)c1 * DM);
            const float4* kp2 = (const float4*)(Kf + base + (size_t)c2 * DM);
            const float4* kp3 = (const float4*)(Kf + base + (size_t)c3 * DM);
            float s0 = 0.f, s1 = 0.f, s2 = 0.f, s3 = 0.f;
            #pragma unroll 1
            for (int q = 0; q < 8; ++q) {
                float4 k0 = kp0[q], k1 = kp1[q], k2 = kp2[q], k3 = kp3[q];
                float4 qv = *(const float4*)&qs[0][4 * q];
                s0 += qv.x*k0.x + qv.y*k0.y + qv.z*k0.z + qv.w*k0.w;
                s1 += qv.x*k1.x + qv.y*k1.y + qv.z*k1.z + qv.w*k1.w;
                s2 += qv.x*k2.x + qv.y*k2.y + qv.z*k2.z + qv.w*k2.w;
                s3 += qv.x*k3.x + qv.y*k3.y + qv.z*k3.z + qv.w*k3.w;
                asm volatile("" ::: "memory");
            }
            unsigned short b0 = f2bf(s0 * scaleL2), b1 = f2bf(s1 * scaleL2);
            unsigned short b2 = f2bf(s2 * scaleL2), b3 = f2bf(s3 * scaleL2);
            {
                int sj = sw8(jb);
                #pragma unroll
                for (int r = 0; r < RT; ++r) SB[r * SRB + sj] = b0;
            }
            if (j1 < njAll) { int sj = sw8(j1);
                #pragma unroll
                for (int r = 0; r < RT; ++r) SB[r * SRB + sj] = b1; }
            if (j2 < njAll) { int sj = sw8(j2);
                #pragma unroll
                for (int r = 0; r < RT; ++r) SB[r * SRB + sj] = b2; }
            if (j3 < njAll) { int sj = sw8(j3);
                #pragma unroll
                for (int r = 0; r < RT; ++r) SB[r * SRB + sj] = b3; }
        }
    } else {
        // MFMA path, 2 chunks per wave-iteration (independent acc chains).
        int wave = t >> 6, lane = t & 63;
        int m = lane & 15, quad = lane >> 4;

        float av[8];
        {
            float4 qa = *(const float4*)&qs[m][8 * quad];
            float4 qb = *(const float4*)&qs[m][8 * quad + 4];
            av[0]=qa.x*scaleL2; av[1]=qa.y*scaleL2; av[2]=qa.z*scaleL2; av[3]=qa.w*scaleL2;
            av[4]=qb.x*scaleL2; av[5]=qb.y*scaleL2; av[6]=qb.z*scaleL2; av[7]=qb.w*scaleL2;
        }
        short8 Ah, Al;
        #pragma unroll
        for (int i = 0; i < 8; ++i) {
            unsigned short hb = f2bf(av[i]);
            Ah[i] = (short)hb;
            Al[i] = (short)f2bf(av[i] - bf2f(hb));
        }

        const unsigned short* KH = KS;
        const unsigned short* KL = KS + (size_t)ROWS * DM;
        size_t rowb = (size_t)b * SEQ;
        int nChunks = (njAll + 15) >> 4;
        #pragma unroll 1
        for (int c = wave; c < nChunks; c += 16) {
            int j0 = c << 4;
            size_t off = (rowb + j0 + m) * DM + h * DK + quad * 8;
            short8 Bh = *(const short8*)&KH[off];
            short8 Bl = *(const short8*)&KL[off];
            bool has2 = (c + 8) < nChunks;       // wave-uniform
            int j0b = j0 + 128;
            f32x4 acc = {0.f, 0.f, 0.f, 0.f};
            f32x4 acc2 = {0.f, 0.f, 0.f, 0.f};
            if (has2) {
                size_t off2 = (rowb + j0b + m) * DM + h * DK + quad * 8;
                short8 Bh2 = *(const short8*)&KH[off2];
                short8 Bl2 = *(const short8*)&KL[off2];
                acc = MFMA_BF16(Ah, Bl, acc, 0, 0, 0);
                acc2 = MFMA_BF16(Ah, Bl2, acc2, 0, 0, 0);
                acc = MFMA_BF16(Al, Bh, acc, 0, 0, 0);
                acc2 = MFMA_BF16(Al, Bh2, acc2, 0, 0, 0);
                acc = MFMA_BF16(Ah, Bh, acc, 0, 0, 0);
                acc2 = MFMA_BF16(Ah, Bh2, acc2, 0, 0, 0);
                int sj = sw8(j0 + m);
                int sj2 = sw8(j0b + m);
                #pragma unroll
                for (int g = 0; g < 4; ++g) {
                    SB[(quad * 4 + g) * SRB + sj] = f2bf(acc[g]);
                    SB[(quad * 4 + g) * SRB + sj2] = f2bf(acc2[g]);
                }
            } else {
                acc = MFMA_BF16(Ah, Bl, acc, 0, 0, 0);
                acc = MFMA_BF16(Al, Bh, acc, 0, 0, 0);
                acc = MFMA_BF16(Ah, Bh, acc, 0, 0, 0);
                int sj = sw8(j0 + m);
                #pragma unroll
                for (int g = 0; g < 4; ++g)
                    SB[(quad * 4 + g) * SRB + sj] = f2bf(acc[g]);
            }
        }
    }
    __syncthreads();

    // ---- Tail fill: bf16 -inf into [nj_r, njPad128) per row ----
    {
        int r = t >> 5, c = t & 31;
        int i = i0 + r;
        int nj = peek ? (i + 1) : i;
        for (int j = nj + c; j < njPad128; j += 32)
            SB[r * SRB + sw8(j)] = 0xFF80u;   // bf16 -inf
    }
    __syncthreads();

    // ---- Phases 2-3 (no-max softmax, mask-free): 32 lanes per row
    {
        int r = t >> 5, c = t & 31;
        int i = i0 + r;
        int nj = peek ? (i + 1) : i;          // only used for l2inv guard
        unsigned short* Sr = SB + r * SRB;
        float gamma2 = -log1pf(__expf(gm[h])) * LOG2E;  // -softplus * log2e

        float l = 0.f;
        #pragma unroll 1
        for (int j4 = 4 * c; j4 < njPad32; j4 += 128) {
            uint2 u = *(const uint2*)&Sr[sw8(j4)];
            l += exp2f(bf2f((unsigned short)u.x));
            l += exp2f(bf2f((unsigned short)(u.x >> 16)));
            l += exp2f(bf2f((unsigned short)u.y));
            l += exp2f(bf2f((unsigned short)(u.y >> 16)));
        }
        #pragma unroll
        for (int off = 16; off; off >>= 1) l += __shfl_xor(l, off, 32);
        float linv = 1.f / l;

        float l2 = 0.f;
        float Bc = 0.f;
        #pragma unroll 1
        for (int k = 0; 128 * k < njPad32; ++k) {
            int j4 = 128 * k + 4 * c;         // may reach njPad128-4: filled
            uint2 u = *(const uint2*)&Sr[sw8(j4)];
            float4 s4;
            s4.x = bf2f((unsigned short)u.x);
            s4.y = bf2f((unsigned short)(u.x >> 16));
            s4.z = bf2f((unsigned short)u.y);
            s4.w = bf2f((unsigned short)(u.y >> 16));
            float e0 = exp2f(s4.x) * linv;
            float e1 = exp2f(s4.y) * linv;
            float e2 = exp2f(s4.z) * linv;
            float e3 = exp2f(s4.w) * linv;
            float sig = e0 + e1 + e2 + e3;
            float x = sig;
            #pragma unroll
            for (int off = 1; off < 32; off <<= 1) {
                float yv = __shfl_up(x, off, 32);
                if (c >= off) x += yv;
            }
            float tot = __shfl(x, 31, 32);
            float cum = Bc + (x - sig);
            Bc += tot;
            float pb = (float)(i - j4);        // per-chunk pos base
            float4 p;
            cum += e0;
            { float dist = sqrtf(fmaxf((1.f - cum) * pb, 0.f));
              float eff = fmaxf(exp2f(dist * gamma2), 1e-5f);   // eff<=1 always
              p.x = exp2f(s4.x * eff); l2 += p.x; }
            cum += e1;
            { float dist = sqrtf(fmaxf((1.f - cum) * (pb - 1.f), 0.f));
              float eff = fmaxf(exp2f(dist * gamma2), 1e-5f);
              p.y = exp2f(s4.y * eff); l2 += p.y; }
            cum += e2;
            { float dist = sqrtf(fmaxf((1.f - cum) * (pb - 2.f), 0.f));
              float eff = fmaxf(exp2f(dist * gamma2), 1e-5f);
              p.z = exp2f(s4.z * eff); l2 += p.z; }
            cum += e3;
            { float dist = sqrtf(fmaxf((1.f - cum) * (pb - 3.f), 0.f));
              float eff = fmaxf(exp2f(dist * gamma2), 1e-5f);
              p.w = exp2f(s4.w * eff); l2 += p.w; }
            ushort4 pk;
            pk.x = f2bf(p.x); pk.y = f2bf(p.y); pk.z = f2bf(p.z); pk.w = f2bf(p.w);
            *(ushort4*)&Sr[sw8(j4)] = pk;     // in-place: exactly the slots read
        }
        #pragma unroll
        for (int off = 16; off; off >>= 1) l2 += __shfl_xor(l2, off, 32);
        if (c == 0) l2inv_s[r] = (nj > 0) ? (1.f / l2) : 0.f;
    }
    __syncthreads();

    // ---- Phase 5 PV: MFMA, 2 chunks per wave-iteration (ILP x2).
    {
        int wave = t >> 6, lane = t & 63;
        int n16 = lane & 15, quad = lane >> 4;
        const unsigned short* VH = VS;
        const unsigned short* VL = VS + (size_t)ROWS * DM;
        size_t vb0 = (size_t)(h * DK + n16) * ROWS + (size_t)b * SEQ;
        size_t vb1 = (size_t)(h * DK + 16 + n16) * ROWS + (size_t)b * SEQ;
        f32x4 oc0 = {0.f,0.f,0.f,0.f}, oc1 = {0.f,0.f,0.f,0.f};
        f32x4 oc0b = {0.f,0.f,0.f,0.f}, oc1b = {0.f,0.f,0.f,0.f};
        #pragma unroll 1
        for (int j0 = wave * 32; j0 < njPad32; j0 += 512) {
            short8 Ap = *(const short8*)&SB[n16 * SRB + sw8(j0 + quad * 8)];
            int jo = j0 + quad * 8;
            short8 Bh0 = *(const short8*)&VH[vb0 + jo];
            short8 Bl0 = *(const short8*)&VL[vb0 + jo];
            short8 Bh1 = *(const short8*)&VH[vb1 + jo];
            short8 Bl1 = *(const short8*)&VL[vb1 + jo];
            int j0b = j0 + 256;
            bool has2 = j0b < njPad32;         // wave-uniform
            if (has2) {
                short8 Ap2 = *(const short8*)&SB[n16 * SRB + sw8(j0b + quad * 8)];
                int jo2 = j0b + quad * 8;
                short8 Bh0b = *(const short8*)&VH[vb0 + jo2];
                short8 Bl0b = *(const short8*)&VL[vb0 + jo2];
                short8 Bh1b = *(const short8*)&VH[vb1 + jo2];
                short8 Bl1b = *(const short8*)&VL[vb1 + jo2];
                oc0 = MFMA_BF16(Ap, Bh0, oc0, 0, 0, 0);
                oc0b = MFMA_BF16(Ap2, Bh0b, oc0b, 0, 0, 0);
                oc0 = MFMA_BF16(Ap, Bl0, oc0, 0, 0, 0);
                oc0b = MFMA_BF16(Ap2, Bl0b, oc0b, 0, 0, 0);
                oc1 = MFMA_BF16(Ap, Bh1, oc1, 0, 0, 0);
                oc1b = MFMA_BF16(Ap2, Bh1b, oc1b, 0, 0, 0);
                oc1 = MFMA_BF16(Ap, Bl1, oc1, 0, 0, 0);
                oc1b = MFMA_BF16(Ap2, Bl1b, oc1b, 0, 0, 0);
            } else {
                oc0 = MFMA_BF16(Ap, Bh0, oc0, 0, 0, 0);
                oc0 = MFMA_BF16(Ap, Bl0, oc0, 0, 0, 0);
                oc1 = MFMA_BF16(Ap, Bh1, oc1, 0, 0, 0);
                oc1 = MFMA_BF16(Ap, Bl1, oc1, 0, 0, 0);
            }
        }
        #pragma unroll
        for (int g = 0; g < 4; ++g) { oc0[g] += oc0b[g]; oc1[g] += oc1b[g]; }
        __syncthreads();          // packed fully consumed -> reuse SB as f32
        float* FS = (float*)SB;
        {   // each wave writes 16 rows x 32 d partials (lane-unique slots)
            #pragma unroll
            for (int g = 0; g < 4; ++g) {
                int row = quad * 4 + g;
                FS[wave * 512 + row * 32 + n16] = oc0[g];
                FS[wave * 512 + row * 32 + 16 + n16] = oc1[g];
            }
        }
    }
    __syncthreads();
    {
        float* FS = (float*)SB;
        int r2 = t >> 5, d = t & 31;
        float sum = 0.f;
        #pragma unroll
        for (int w = 0; w < 8; ++w)
            sum += FS[w * 512 + r2 * 32 + d];
        int ii = i0 + r2;
        O[base + (size_t)ii * DM + d] = sum * l2inv_s[r2];
    }
}

// ---------- small precompute: q3row = know@W3q+b3q; key8 = sigmoid heads ---
__global__ __launch_bounds__(256) void precompute_kernel(
    const float* __restrict__ know,
    const float* __restrict__ W3q, const float* __restrict__ b3q,
    const float* __restrict__ lkW, const float* __restrict__ lkb,
    float* __restrict__ q3row, float* __restrict__ key8)
{
    __shared__ float kn[DM];
    int t = threadIdx.x;
    kn[t] = know[t];
    __syncthreads();
    float acc = b3q[t];
    for (int c = 0; c < DM; ++c) acc += kn[c] * W3q[(size_t)c * DM + t];
    q3row[t] = acc;
    float bk = lkb[t];
    for (int h = 0; h < NH; ++h) {
        float a = bk;
        #pragma unroll
        for (int c = 0; c < DK; ++c) a += kn[h * DK + c] * lkW[(size_t)c * DM + t];
        key8[(size_t)h * DM + t] = 1.f / (1.f + __expf(-a));
    }
}

// ---------- final readout (f32 output), single-barrier beta reduction ------
__global__ __launch_bounds__(256) void readout_kernel(
    const float* __restrict__ h3, const float* __restrict__ qe,
    const float* __restrict__ key8,
    const float* __restrict__ lvW, const float* __restrict__ lvb,
    float* __restrict__ out)
{
    __shared__ float hrow[DM], qrow[DM];
    __shared__ float red8[4][NH];
    int n = blockIdx.x, t = threadIdx.x;
    int lane = t & 63, wid = t >> 6;
    hrow[t] = h3[(size_t)n * DM + t];
    qrow[t] = qe[(size_t)n * DM + t];
    __syncthreads();
    float ph[NH];
    #pragma unroll
    for (int h = 0; h < NH; ++h) {
        float v = key8[(size_t)h * DM + t] * qrow[t];
        v = waveRedSum(v);
        ph[h] = v;
    }
    if (lane == 0) {
        #pragma unroll
        for (int h = 0; h < NH; ++h) red8[wid][h] = ph[h];
    }
    __syncthreads();
    float beta[NH];
    #pragma unroll
    for (int h = 0; h < NH; ++h)
        beta[h] = red8[0][h] + red8[1][h] + red8[2][h] + red8[3][h];
    float bv = lvb[t];
    float vh[NH];
    for (int h = 0; h < NH; ++h) {
        float a = bv;
        #pragma unroll
        for (int c = 0; c < DK; ++c) a += hrow[h * DK + c] * lvW[(size_t)c * DM + t];
        vh[h] = 1.f / (1.f + __expf(-a));
    }
    float mb = beta[0];
    #pragma unroll
    for (int h = 1; h < NH; ++h) mb = fmaxf(mb, beta[h]);
    float se = 0.f, eh[NH];
    #pragma unroll
    for (int h = 0; h < NH; ++h) { eh[h] = __expf(beta[h] - mb); se += eh[h]; }
    float sinv = 1.f / se;
    float o = 0.f;
    #pragma unroll
    for (int h = 0; h < NH; ++h) o += eh[h] * sinv * vh[h];
    out[(size_t)n * DM + t] = o;
}

extern "C" void kernel_launch(void* const* d_in, const int* in_sizes, int n_in,
                              void* d_out, int out_size, void* d_ws, size_t ws_size,
                              hipStream_t stream) {
    (void)in_sizes; (void)n_in; (void)out_size; (void)ws_size;
    const float* q_emb  = (const float*)d_in[0];
    const float* qa_emb = (const float*)d_in[1];
    const float* b1_Wq = (const float*)d_in[2];
    const float* b1_bq = (const float*)d_in[3];
    const float* b1_Wv = (const float*)d_in[4];
    const float* b1_bv = (const float*)d_in[5];
    const float* b1_Wo = (const float*)d_in[6];
    const float* b1_bo = (const float*)d_in[7];
    const float* b1_gam = (const float*)d_in[8];
    const float* b1_lng = (const float*)d_in[9];
    const float* b1_lnb = (const float*)d_in[10];
    const float* b2_Wq = (const float*)d_in[11];
    const float* b2_bq = (const float*)d_in[12];
    const float* b2_Wv = (const float*)d_in[13];
    const float* b2_bv = (const float*)d_in[14];
    const float* b2_Wo = (const float*)d_in[15];
    const float* b2_bo = (const float*)d_in[16];
    const float* b2_gam = (const float*)d_in[17];
    const float* b2_lng = (const float*)d_in[18];
    const float* b2_lnb = (const float*)d_in[19];
    const float* b3_Wq = (const float*)d_in[20];
    const float* b3_bq = (const float*)d_in[21];
    const float* b3_Wk = (const float*)d_in[22];
    const float* b3_bk = (const float*)d_in[23];
    const float* b3_Wv = (const float*)d_in[24];
    const float* b3_bv = (const float*)d_in[25];
    const float* b3_Wo = (const float*)d_in[26];
    const float* b3_bo = (const float*)d_in[27];
    const float* b3_gam = (const float*)d_in[28];
    const float* b3_lng = (const float*)d_in[29];
    const float* b3_lnb = (const float*)d_in[30];
    const float* know  = (const float*)d_in[31];
    const float* lk_W  = (const float*)d_in[32];
    const float* lk_b  = (const float*)d_in[33];
    const float* lv_W  = (const float*)d_in[34];
    const float* lv_b  = (const float*)d_in[35];

    const size_t SLAB = (size_t)ROWS * DM;  // 1,048,576 floats = 4 MB
    const size_t USLAB = 2 * SLAB;          // split-bf16 buffer (hi+lo), ushorts
    float* A1 = (float*)d_ws;               // q1k1 f32; later k3
    float* A2 = A1 + SLAB;                  // q2k2 f32
    float* C1 = A2 + SLAB;                  // att1 out; later att3 out
    float* C2 = C1 + SLAB;                  // att2 out; later h3
    unsigned short* KS1 = (unsigned short*)(C2 + SLAB);  // later hq (f32)
    unsigned short* KS2 = KS1 + USLAB;                   // later ha (f32)
    unsigned short* VS1 = KS2 + USLAB;                   // later VS3
    unsigned short* VS2 = VS1 + USLAB;
    float* q3row = (float*)(VS2 + USLAB);   // 256
    float* key8  = q3row + DM;              // 8*256
    unsigned short* Wsp = (unsigned short*)(key8 + NH * DM);  // 9 x 256KB
    float* hq = (float*)KS1;
    float* ha = (float*)KS2;
    float* k3 = A1;
    unsigned short* VS3 = VS1;
    float* O3 = C1;
    float* h3 = C2;

    auto WH = [&](int i) { return Wsp + (size_t)i * 131072; };
    // 0:b1_Wq 1:b1_Wv 2:b1_Wo 3:b2_Wq 4:b2_Wv 5:b2_Wo 6:b3_Wk 7:b3_Wv 8:b3_Wo

    dim3 blk(256);
    dim3 ablk(512);
    dim3 agrid2(SEQ / RT, 32);        // dual-set attention (128 x 32)
    dim3 agrid1(SEQ / RT, 16);        // single-set attention
    dim3 rgrid(ROWS);

    convert_w_kernel<<<dim3(64, 9), blk, 0, stream>>>(
        b1_Wq, b1_Wv, b1_Wo, b2_Wq, b2_Wv, b2_Wo, b3_Wk, b3_Wv, b3_Wo, Wsp);

    precompute_kernel<<<dim3(1), blk, 0, stream>>>(know, b3_Wq, b3_bq, lk_W, lk_b, q3row, key8);

    // ---- blocks 1+2 projections: q/k f32+rowsplit, v transposed-split ----
    gemm4_kernel<<<dim3(ROWS/16, 4), blk, 0, stream>>>(
        q_emb,  WH(0), b1_bq, A1,      KS1,     nullptr,
        q_emb,  WH(1), b1_bv, nullptr, nullptr, VS1,
        qa_emb, WH(3), b2_bq, A2,      KS2,     nullptr,
        qa_emb, WH(4), b2_bv, nullptr, nullptr, VS2);

    // ---- blocks 1+2 attention (one dual-set launch) ----
    attn_tile_kernel<<<agrid2, ablk, 0, stream>>>(
        A1, nullptr, KS1, VS1, b1_gam, C1,
        A2, nullptr, KS2, VS2, b2_gam, C2, 1, 0);

    // ---- output projections + residual + LN (fused) -> hq, ha ----
    gemm_ln2_kernel<<<dim3(ROWS/16, 2), blk, 0, stream>>>(
        C1, WH(2), b1_bo, q_emb,  b1_lng, b1_lnb, hq, 0,
        C2, WH(5), b2_bo, qa_emb, b2_lng, b2_lnb, ha, 0);

    // ---- block 3: k3 = hq@W3k (f32), v3 = ha@W3v (transposed split) ----
    gemm4_kernel<<<dim3(ROWS/16, 2), blk, 0, stream>>>(
        hq, WH(6), b3_bk, k3,      nullptr, nullptr,
        ha, WH(7), b3_bv, nullptr, nullptr, VS3,
        hq, WH(6), b3_bk, k3,      nullptr, nullptr,   // unused sets
        hq, WH(6), b3_bk, k3,      nullptr, nullptr);

    attn_tile_kernel<<<agrid1, ablk, 0, stream>>>(
        q3row, k3, nullptr, VS3, b3_gam, O3,
        q3row, k3, nullptr, VS3, b3_gam, O3, 0, 1);

    // ---- y3 + know-residual + LN (fused) -> h3 ----
    gemm_ln2_kernel<<<dim3(ROWS/16, 1), blk, 0, stream>>>(
        O3, WH(8), b3_bo, know, b3_lng, b3_lnb, h3, 1,
        O3, WH(8), b3_bo, know, b3_lng, b3_lnb, h3, 1);

    readout_kernel<<<rgrid, blk, 0, stream>>>(h3, q_emb, key8, lv_W, lv_b,
                                              (float*)d_out);
}

// Round 24
// 633.694 us; speedup vs baseline: 1.0040x; 1.0040x over previous
//
#include <hip/hip_runtime.h>
#include <hip/hip_bf16.h>

#define DM 256
#define NH 8
#define DK 32
#define BSZ 2
#define SEQ 2048
#define ROWS (BSZ*SEQ)   // 4096
#define RT 16            // query rows per attention tile (full MFMA rows)
#define SRB 2312         // ushort row stride; swizzle phys = j + 8*(j>>6), max 2295

static __device__ __forceinline__ int sw8(int j) { return j + ((j >> 6) << 3); }

typedef __attribute__((ext_vector_type(8))) short short8;
typedef __attribute__((ext_vector_type(4))) float f32x4;

// f32 -> bf16 bits, round-to-nearest-even (validated r15)
static __device__ __forceinline__ unsigned short f2bf(float f) {
    unsigned u = __float_as_uint(f);
    return (unsigned short)((u + 0x7FFFu + ((u >> 16) & 1u)) >> 16);
}
static __device__ __forceinline__ float bf2f(unsigned short h) {
    return __uint_as_float(((unsigned)h) << 16);
}

#define MFMA_BF16 __builtin_amdgcn_mfma_f32_16x16x32_bf16
#define LOG2E 1.44269504088896340736f

// ---------- reduction helpers ----------
static __device__ __forceinline__ float waveRedSum(float v) {
    #pragma unroll
    for (int off = 32; off > 0; off >>= 1) v += __shfl_down(v, off, 64);
    return v;
}

// ---------- one-time: weights -> split-bf16, transposed [n][k] ----------
__global__ __launch_bounds__(256) void convert_w_kernel(
    const float* __restrict__ S0, const float* __restrict__ S1, const float* __restrict__ S2,
    const float* __restrict__ S3, const float* __restrict__ S4, const float* __restrict__ S5,
    const float* __restrict__ S6, const float* __restrict__ S7, const float* __restrict__ S8,
    unsigned short* __restrict__ dst)
{
    const float* W;
    int s = blockIdx.y;
    if (s == 0) W = S0; else if (s == 1) W = S1; else if (s == 2) W = S2;
    else if (s == 3) W = S3; else if (s == 4) W = S4; else if (s == 5) W = S5;
    else if (s == 6) W = S6; else if (s == 7) W = S7; else W = S8;
    unsigned short* H = dst + (size_t)s * 131072;
    unsigned short* L = H + 65536;

    int e = blockIdx.x * 1024 + threadIdx.x * 4;
    int k = e >> 8, n = e & 255;
    float4 w4 = *(const float4*)(W + e);
    float v[4] = {w4.x, w4.y, w4.z, w4.w};
    #pragma unroll
    for (int i = 0; i < 4; ++i) {
        unsigned short h = f2bf(v[i]);
        H[(size_t)(n + i) * 256 + k] = h;
        L[(size_t)(n + i) * 256 + k] = (unsigned short)f2bf(v[i] - bf2f(h));
    }
}

// ---------- batched MFMA GEMM (16x256/block, 4 sets) with optional ----------
// split-bf16 side outputs: KSo = [row][col] hi/lo; VSo = [col][row] hi/lo.
__global__ __launch_bounds__(256) void gemm4_kernel(
    const float* __restrict__ X0, const unsigned short* __restrict__ H0, const float* __restrict__ B0,
    float* __restrict__ Y0, unsigned short* __restrict__ K0o, unsigned short* __restrict__ V0o,
    const float* __restrict__ X1, const unsigned short* __restrict__ H1, const float* __restrict__ B1,
    float* __restrict__ Y1, unsigned short* __restrict__ K1o, unsigned short* __restrict__ V1o,
    const float* __restrict__ X2, const unsigned short* __restrict__ H2, const float* __restrict__ B2,
    float* __restrict__ Y2, unsigned short* __restrict__ K2o, unsigned short* __restrict__ V2o,
    const float* __restrict__ X3, const unsigned short* __restrict__ H3, const float* __restrict__ B3,
    float* __restrict__ Y3, unsigned short* __restrict__ K3o, unsigned short* __restrict__ V3o)
{
    const float *X, *Bias; const unsigned short* H; float* Yf;
    unsigned short *KSo, *VSo;
    int s = blockIdx.y;
    if (s == 0)      { X = X0; H = H0; Bias = B0; Yf = Y0; KSo = K0o; VSo = V0o; }
    else if (s == 1) { X = X1; H = H1; Bias = B1; Yf = Y1; KSo = K1o; VSo = V1o; }
    else if (s == 2) { X = X2; H = H2; Bias = B2; Yf = Y2; KSo = K2o; VSo = V2o; }
    else             { X = X3; H = H3; Bias = B3; Yf = Y3; KSo = K3o; VSo = V3o; }
    const unsigned short* L = H + 65536;

    __shared__ __align__(16) unsigned short XhL[16 * 264];
    __shared__ __align__(16) unsigned short XlL[16 * 264];
    int t = threadIdx.x;
    int r0 = blockIdx.x * 16;
    {   // stage X tile as split bf16
        int r = t >> 4, c0 = (t & 15) * 16;
        const float* xp = X + (size_t)(r0 + r) * DM + c0;
        #pragma unroll
        for (int i = 0; i < 16; i += 4) {
            float4 v4 = *(const float4*)(xp + i);
            float vv[4] = {v4.x, v4.y, v4.z, v4.w};
            #pragma unroll
            for (int j = 0; j < 4; ++j) {
                unsigned short h = f2bf(vv[j]);
                XhL[r * 264 + c0 + i + j] = h;
                XlL[r * 264 + c0 + i + j] = (unsigned short)f2bf(vv[j] - bf2f(h));
            }
        }
    }
    __syncthreads();
    int lane = t & 63, wv = t >> 6;
    int m = lane & 15, quad = lane >> 4;
    f32x4 aa[4];
    #pragma unroll
    for (int nt = 0; nt < 4; ++nt) { aa[nt][0]=0.f; aa[nt][1]=0.f; aa[nt][2]=0.f; aa[nt][3]=0.f; }
    #pragma unroll 1
    for (int kc = 0; kc < 8; ++kc) {
        int k0 = kc * 32;
        short8 Ah = *(const short8*)&XhL[m * 264 + k0 + quad * 8];
        short8 Al = *(const short8*)&XlL[m * 264 + k0 + quad * 8];
        size_t boff = (size_t)(wv * 64 + m) * 256 + k0 + quad * 8;
        #pragma unroll
        for (int nt = 0; nt < 4; ++nt) {
            short8 Bh = *(const short8*)(H + boff + nt * 16 * 256);
            short8 Bl = *(const short8*)(L + boff + nt * 16 * 256);
            aa[nt] = MFMA_BF16(Al, Bh, aa[nt], 0, 0, 0);
            aa[nt] = MFMA_BF16(Ah, Bl, aa[nt], 0, 0, 0);
            aa[nt] = MFMA_BF16(Ah, Bh, aa[nt], 0, 0, 0);
        }
    }
    // epilogue: D col = lane&15 (+16*nt +64*wv), row = quad*4+g
    int col0 = wv * 64 + m;
    #pragma unroll
    for (int nt = 0; nt < 4; ++nt) {
        int col = col0 + nt * 16;
        float bb = Bias[col];
        float yv[4];
        #pragma unroll
        for (int g = 0; g < 4; ++g) yv[g] = aa[nt][g] + bb;
        if (Yf) {
            #pragma unroll
            for (int g = 0; g < 4; ++g)
                Yf[(size_t)(r0 + quad * 4 + g) * DM + col] = yv[g];
        }
        if (KSo) {
            unsigned short* KH = KSo;
            unsigned short* KL = KSo + (size_t)ROWS * DM;
            #pragma unroll
            for (int g = 0; g < 4; ++g) {
                unsigned short hb = f2bf(yv[g]);
                KH[(size_t)(r0 + quad * 4 + g) * DM + col] = hb;
                KL[(size_t)(r0 + quad * 4 + g) * DM + col] =
                    (unsigned short)f2bf(yv[g] - bf2f(hb));
            }
        }
        if (VSo) {
            unsigned short* VH = VSo;
            unsigned short* VL = VSo + (size_t)ROWS * DM;
            ushort4 h4, l4;
            unsigned short hb;
            hb = f2bf(yv[0]); h4.x = hb; l4.x = (unsigned short)f2bf(yv[0] - bf2f(hb));
            hb = f2bf(yv[1]); h4.y = hb; l4.y = (unsigned short)f2bf(yv[1] - bf2f(hb));
            hb = f2bf(yv[2]); h4.z = hb; l4.z = (unsigned short)f2bf(yv[2] - bf2f(hb));
            hb = f2bf(yv[3]); h4.w = hb; l4.w = (unsigned short)f2bf(yv[3] - bf2f(hb));
            *(ushort4*)&VH[(size_t)col * ROWS + r0 + quad * 4] = h4;
            *(ushort4*)&VL[(size_t)col * ROWS + r0 + quad * 4] = l4;
        }
    }
}

// ---------- MFMA GEMM + residual + LayerNorm fused (2 sets) ----------
__global__ __launch_bounds__(256) void gemm_ln2_kernel(
    const float* __restrict__ X0, const unsigned short* __restrict__ H0, const float* __restrict__ B0,
    const float* __restrict__ R0, const float* __restrict__ G0, const float* __restrict__ L0,
    float* __restrict__ Y0, int bc0,
    const float* __restrict__ X1, const unsigned short* __restrict__ H1, const float* __restrict__ B1,
    const float* __restrict__ R1, const float* __restrict__ G1, const float* __restrict__ L1,
    float* __restrict__ Y1, int bc1)
{
    const float *X, *Bias, *R, *G, *Lb; const unsigned short* H; float* Y; int bc;
    if (blockIdx.y == 0) { X=X0; H=H0; Bias=B0; R=R0; G=G0; Lb=L0; Y=Y0; bc=bc0; }
    else                 { X=X1; H=H1; Bias=B1; R=R1; G=G1; Lb=L1; Y=Y1; bc=bc1; }
    const unsigned short* L = H + 65536;

    __shared__ __align__(16) unsigned short XhL[16 * 264];
    __shared__ __align__(16) unsigned short XlL[16 * 264];
    __shared__ __align__(16) float yl[16 * 260];
    int t = threadIdx.x;
    int r0 = blockIdx.x * 16;
    {   int r = t >> 4, c0 = (t & 15) * 16;
        const float* xp = X + (size_t)(r0 + r) * DM + c0;
        #pragma unroll
        for (int i = 0; i < 16; i += 4) {
            float4 v4 = *(const float4*)(xp + i);
            float vv[4] = {v4.x, v4.y, v4.z, v4.w};
            #pragma unroll
            for (int j = 0; j < 4; ++j) {
                unsigned short h = f2bf(vv[j]);
                XhL[r * 264 + c0 + i + j] = h;
                XlL[r * 264 + c0 + i + j] = (unsigned short)f2bf(vv[j] - bf2f(h));
            }
        }
    }
    __syncthreads();
    int lane = t & 63, wv = t >> 6;
    int m = lane & 15, quad = lane >> 4;
    f32x4 aa[4];
    #pragma unroll
    for (int nt = 0; nt < 4; ++nt) { aa[nt][0]=0.f; aa[nt][1]=0.f; aa[nt][2]=0.f; aa[nt][3]=0.f; }
    #pragma unroll 1
    for (int kc = 0; kc < 8; ++kc) {
        int k0 = kc * 32;
        short8 Ah = *(const short8*)&XhL[m * 264 + k0 + quad * 8];
        short8 Al = *(const short8*)&XlL[m * 264 + k0 + quad * 8];
        size_t boff = (size_t)(wv * 64 + m) * 256 + k0 + quad * 8;
        #pragma unroll
        for (int nt = 0; nt < 4; ++nt) {
            short8 Bh = *(const short8*)(H + boff + nt * 16 * 256);
            short8 Bl = *(const short8*)(L + boff + nt * 16 * 256);
            aa[nt] = MFMA_BF16(Al, Bh, aa[nt], 0, 0, 0);
            aa[nt] = MFMA_BF16(Ah, Bl, aa[nt], 0, 0, 0);
            aa[nt] = MFMA_BF16(Ah, Bh, aa[nt], 0, 0, 0);
        }
    }
    {
        int col0 = wv * 64 + m;
        #pragma unroll
        for (int nt = 0; nt < 4; ++nt) {
            int col = col0 + nt * 16;
            float bb = Bias[col];
            #pragma unroll
            for (int g = 0; g < 4; ++g) {
                int row = quad * 4 + g;
                float res = bc ? R[col] : R[(size_t)(r0 + row) * DM + col];
                yl[row * 260 + col] = aa[nt][g] + bb + res;
            }
        }
    }
    __syncthreads();
    {
        int r = t >> 4, c0 = (t & 15) * 16;
        float vals[16];
        float part = 0.f;
        #pragma unroll
        for (int i = 0; i < 16; ++i) { vals[i] = yl[r * 260 + c0 + i]; part += vals[i]; }
        #pragma unroll
        for (int off = 8; off; off >>= 1) part += __shfl_xor(part, off, 16);
        float mean = part * (1.f / DM);
        float vp = 0.f;
        #pragma unroll
        for (int i = 0; i < 16; ++i) { float d = vals[i] - mean; vp += d * d; }
        #pragma unroll
        for (int off = 8; off; off >>= 1) vp += __shfl_xor(vp, off, 16);
        float rs = rsqrtf(vp * (1.f / DM) + 1e-5f);
        float* yp = Y + (size_t)(r0 + r) * DM + c0;
        #pragma unroll
        for (int i = 0; i < 16; i += 4) {
            float4 o;
            o.x = (vals[i+0] - mean) * rs * G[c0+i+0] + Lb[c0+i+0];
            o.y = (vals[i+1] - mean) * rs * G[c0+i+1] + Lb[c0+i+1];
            o.z = (vals[i+2] - mean) * rs * G[c0+i+2] + Lb[c0+i+2];
            o.w = (vals[i+3] - mean) * rs * G[c0+i+3] + Lb[c0+i+3];
            *(float4*)(yp + i) = o;
        }
    }
}

// ---------- tiled attention with distance-decay bias ----------
// RT=16 + 512 threads (r22 loop forms — r23 ILP dup was neutral). MFMA path
// fuses the row-sum l into phase 1 (per-lane exp2 partials + shfl reduce +
// 512B LDS), eliminating pass B for blocks 1/2. qbcast keeps pass B.
__global__ __launch_bounds__(512) void attn_tile_kernel(
    const float* __restrict__ Q0, const float* __restrict__ Kf0,
    const unsigned short* __restrict__ KS0, const unsigned short* __restrict__ VS0,
    const float* __restrict__ g0, float* __restrict__ O0,
    const float* __restrict__ Q1, const float* __restrict__ Kf1,
    const unsigned short* __restrict__ KS1, const unsigned short* __restrict__ VS1,
    const float* __restrict__ g1, float* __restrict__ O1,
    int peek, int qbcast)
{
    __shared__ __align__(16) unsigned short SB[RT * SRB];
    __shared__ float qs[RT][DK];
    __shared__ float l2inv_s[RT];
    __shared__ float rowsum[8 * RT];   // per-wave partial l (MFMA path)

    int y = blockIdx.y;
    int set = y >> 4, bh = y & 15;
    const float* Q = set ? Q1 : Q0;
    const float* Kf = set ? Kf1 : Kf0;
    const unsigned short* KS = set ? KS1 : KS0;
    const unsigned short* VS = set ? VS1 : VS0;
    const float* gm = set ? g1 : g0;
    float* O = set ? O1 : O0;

    int b = bh >> 3, h = bh & 7;
    int i0 = ((int)gridDim.x - 1 - (int)blockIdx.x) * RT;   // largest-first
    int t = threadIdx.x;
    size_t base = ((size_t)b * SEQ) * DM + (size_t)h * DK;

    {   // load Q tile (512 threads = 16 rows x 32)
        int r = t >> 5, d = t & 31;
        qs[r][d] = qbcast ? Q[(size_t)h * DK + d]
                          : Q[base + (size_t)(i0 + r) * DM + d];
    }
    __syncthreads();

    int njAll = peek ? (i0 + RT) : (i0 + RT - 1);  // >= 15 always
    int njPad32 = (njAll + 31) & ~31;
    int njPad128 = (njAll + 127) & ~127;           // pass-C read extent
    const float scaleL2 = 0.17677669529663687f * LOG2E;   // 1/sqrt(32)*log2e

    // ---- Phase 1: scores (log2-domain bf16 into SB).
    if (qbcast) {
        #pragma unroll 1
        for (int jb = t; jb < njAll; jb += 2048) {
            int j1 = jb + 512, j2 = jb + 1024, j3 = jb + 1536;
            int c1 = j1 < njAll ? j1 : jb;
            int c2 = j2 < njAll ? j2 : jb;
            int c3 = j3 < njAll ? j3 : jb;
            const float4* kp0 = (const float4*)(Kf + base + (size_t)jb * DM);
            const float4* kp1 = (const float4*)(Kf + base + (size_t)c1 * DM);
            const float4* kp2 = (const float4*)(Kf + base + (size_t)c2 * DM);
            const float4* kp3 = (const float4*)(Kf + base + (size_t)c3 * DM);
            float s0 = 0.f, s1 = 0.f, s2 = 0.f, s3 = 0.f;
            #pragma unroll 1
            for (int q = 0; q < 8; ++q) {
                float4 k0 = kp0[q], k1 = kp1[q], k2 = kp2[q], k3 = kp3[q];
                float4 qv = *(const float4*)&qs[0][4 * q];
                s0 += qv.x*k0.x + qv.y*k0.y + qv.z*k0.z + qv.w*k0.w;
                s1 += qv.x*k1.x + qv.y*k1.y + qv.z*k1.z + qv.w*k1.w;
                s2 += qv.x*k2.x + qv.y*k2.y + qv.z*k2.z + qv.w*k2.w;
                s3 += qv.x*k3.x + qv.y*k3.y + qv.z*k3.z + qv.w*k3.w;
                asm volatile("" ::: "memory");
            }
            unsigned short b0 = f2bf(s0 * scaleL2), b1 = f2bf(s1 * scaleL2);
            unsigned short b2 = f2bf(s2 * scaleL2), b3 = f2bf(s3 * scaleL2);
            {
                int sj = sw8(jb);
                #pragma unroll
                for (int r = 0; r < RT; ++r) SB[r * SRB + sj] = b0;
            }
            if (j1 < njAll) { int sj = sw8(j1);
                #pragma unroll
                for (int r = 0; r < RT; ++r) SB[r * SRB + sj] = b1; }
            if (j2 < njAll) { int sj = sw8(j2);
                #pragma unroll
                for (int r = 0; r < RT; ++r) SB[r * SRB + sj] = b2; }
            if (j3 < njAll) { int sj = sw8(j3);
                #pragma unroll
                for (int r = 0; r < RT; ++r) SB[r * SRB + sj] = b3; }
        }
    } else {
        // MFMA path + fused per-row exp2 partial sums (kills pass B).
        int wave = t >> 6, lane = t & 63;
        int m = lane & 15, quad = lane >> 4;

        float av[8];
        {
            float4 qa = *(const float4*)&qs[m][8 * quad];
            float4 qb = *(const float4*)&qs[m][8 * quad + 4];
            av[0]=qa.x*scaleL2; av[1]=qa.y*scaleL2; av[2]=qa.z*scaleL2; av[3]=qa.w*scaleL2;
            av[4]=qb.x*scaleL2; av[5]=qb.y*scaleL2; av[6]=qb.z*scaleL2; av[7]=qb.w*scaleL2;
        }
        short8 Ah, Al;
        #pragma unroll
        for (int i = 0; i < 8; ++i) {
            unsigned short hb = f2bf(av[i]);
            Ah[i] = (short)hb;
            Al[i] = (short)f2bf(av[i] - bf2f(hb));
        }

        const unsigned short* KH = KS;
        const unsigned short* KL = KS + (size_t)ROWS * DM;
        size_t rowb = (size_t)b * SEQ;
        int njr0 = i0 + quad * 4 + peek;      // nj of row quad*4
        float rp0 = 0.f, rp1 = 0.f, rp2 = 0.f, rp3 = 0.f;
        int nChunks = (njAll + 15) >> 4;
        #pragma unroll 1
        for (int c = wave; c < nChunks; c += 8) {
            int j0 = c << 4;
            size_t off = (rowb + j0 + m) * DM + h * DK + quad * 8;
            short8 Bh = *(const short8*)&KH[off];
            short8 Bl = *(const short8*)&KL[off];
            f32x4 acc = {0.f, 0.f, 0.f, 0.f};
            acc = MFMA_BF16(Ah, Bl, acc, 0, 0, 0);
            acc = MFMA_BF16(Al, Bh, acc, 0, 0, 0);
            acc = MFMA_BF16(Ah, Bh, acc, 0, 0, 0);
            int jcol = j0 + m;
            int sj = sw8(jcol);
            #pragma unroll
            for (int g = 0; g < 4; ++g)
                SB[(quad * 4 + g) * SRB + sj] = f2bf(acc[g]);
            rp0 += (jcol < njr0 + 0) ? exp2f(acc[0]) : 0.f;
            rp1 += (jcol < njr0 + 1) ? exp2f(acc[1]) : 0.f;
            rp2 += (jcol < njr0 + 2) ? exp2f(acc[2]) : 0.f;
            rp3 += (jcol < njr0 + 3) ? exp2f(acc[3]) : 0.f;
        }
        // reduce across the 16 m-lanes of each quad group
        #pragma unroll
        for (int off = 1; off < 16; off <<= 1) {
            rp0 += __shfl_xor(rp0, off, 64);
            rp1 += __shfl_xor(rp1, off, 64);
            rp2 += __shfl_xor(rp2, off, 64);
            rp3 += __shfl_xor(rp3, off, 64);
        }
        if (m == 0) {
            rowsum[wave * RT + quad * 4 + 0] = rp0;
            rowsum[wave * RT + quad * 4 + 1] = rp1;
            rowsum[wave * RT + quad * 4 + 2] = rp2;
            rowsum[wave * RT + quad * 4 + 3] = rp3;
        }
    }
    __syncthreads();

    // ---- Tail fill: bf16 -inf into [nj_r, njPad128) per row ----
    {
        int r = t >> 5, c = t & 31;
        int i = i0 + r;
        int nj = peek ? (i + 1) : i;
        for (int j = nj + c; j < njPad128; j += 32)
            SB[r * SRB + sw8(j)] = 0xFF80u;   // bf16 -inf
    }
    __syncthreads();

    // ---- Phases 2-3 (no-max softmax, mask-free): 32 lanes per row
    {
        int r = t >> 5, c = t & 31;
        int i = i0 + r;
        int nj = peek ? (i + 1) : i;          // only used for l2inv guard
        unsigned short* Sr = SB + r * SRB;
        float gamma2 = -log1pf(__expf(gm[h])) * LOG2E;  // -softplus * log2e

        float l;
        if (qbcast) {
            l = 0.f;
            #pragma unroll 1
            for (int j4 = 4 * c; j4 < njPad32; j4 += 128) {
                uint2 u = *(const uint2*)&Sr[sw8(j4)];
                l += exp2f(bf2f((unsigned short)u.x));
                l += exp2f(bf2f((unsigned short)(u.x >> 16)));
                l += exp2f(bf2f((unsigned short)u.y));
                l += exp2f(bf2f((unsigned short)(u.y >> 16)));
            }
            #pragma unroll
            for (int off = 16; off; off >>= 1) l += __shfl_xor(l, off, 32);
        } else {
            l = 0.f;
            #pragma unroll
            for (int w = 0; w < 8; ++w) l += rowsum[w * RT + r];
        }
        float linv = 1.f / l;

        float l2 = 0.f;
        float Bc = 0.f;
        #pragma unroll 1
        for (int k = 0; 128 * k < njPad32; ++k) {
            int j4 = 128 * k + 4 * c;         // may reach njPad128-4: filled
            uint2 u = *(const uint2*)&Sr[sw8(j4)];
            float4 s4;
            s4.x = bf2f((unsigned short)u.x);
            s4.y = bf2f((unsigned short)(u.x >> 16));
            s4.z = bf2f((unsigned short)u.y);
            s4.w = bf2f((unsigned short)(u.y >> 16));
            float e0 = exp2f(s4.x) * linv;
            float e1 = exp2f(s4.y) * linv;
            float e2 = exp2f(s4.z) * linv;
            float e3 = exp2f(s4.w) * linv;
            float sig = e0 + e1 + e2 + e3;
            float x = sig;
            #pragma unroll
            for (int off = 1; off < 32; off <<= 1) {
                float yv = __shfl_up(x, off, 32);
                if (c >= off) x += yv;
            }
            float tot = __shfl(x, 31, 32);
            float cum = Bc + (x - sig);
            Bc += tot;
            float pb = (float)(i - j4);        // per-chunk pos base
            float4 p;
            cum += e0;
            { float dist = sqrtf(fmaxf((1.f - cum) * pb, 0.f));
              float eff = fmaxf(exp2f(dist * gamma2), 1e-5f);   // eff<=1 always
              p.x = exp2f(s4.x * eff); l2 += p.x; }
            cum += e1;
            { float dist = sqrtf(fmaxf((1.f - cum) * (pb - 1.f), 0.f));
              float eff = fmaxf(exp2f(dist * gamma2), 1e-5f);
              p.y = exp2f(s4.y * eff); l2 += p.y; }
            cum += e2;
            { float dist = sqrtf(fmaxf((1.f - cum) * (pb - 2.f), 0.f));
              float eff = fmaxf(exp2f(dist * gamma2), 1e-5f);
              p.z = exp2f(s4.z * eff); l2 += p.z; }
            cum += e3;
            { float dist = sqrtf(fmaxf((1.f - cum) * (pb - 3.f), 0.f));
              float eff = fmaxf(exp2f(dist * gamma2), 1e-5f);
              p.w = exp2f(s4.w * eff); l2 += p.w; }
            ushort4 pk;
            pk.x = f2bf(p.x); pk.y = f2bf(p.y); pk.z = f2bf(p.z); pk.w = f2bf(p.w);
            *(ushort4*)&Sr[sw8(j4)] = pk;     // in-place: exactly the slots read
        }
        #pragma unroll
        for (int off = 16; off; off >>= 1) l2 += __shfl_xor(l2, off, 32);
        if (c == 0) l2inv_s[r] = (nj > 0) ? (1.f / l2) : 0.f;
    }
    __syncthreads();

    // ---- Phase 5 PV: MFMA, P bf16 in SB (A, 16 rows all used), split V (B).
    {
        int wave = t >> 6, lane = t & 63;
        int n16 = lane & 15, quad = lane >> 4;
        const unsigned short* VH = VS;
        const unsigned short* VL = VS + (size_t)ROWS * DM;
        size_t vb0 = (size_t)(h * DK + n16) * ROWS + (size_t)b * SEQ;
        size_t vb1 = (size_t)(h * DK + 16 + n16) * ROWS + (size_t)b * SEQ;
        f32x4 oc0 = {0.f,0.f,0.f,0.f}, oc1 = {0.f,0.f,0.f,0.f};
        #pragma unroll 1
        for (int j0 = wave * 32; j0 < njPad32; j0 += 256) {
            short8 Ap = *(const short8*)&SB[n16 * SRB + sw8(j0 + quad * 8)];
            int jo = j0 + quad * 8;
            short8 Bh0 = *(const short8*)&VH[vb0 + jo];
            short8 Bl0 = *(const short8*)&VL[vb0 + jo];
            short8 Bh1 = *(const short8*)&VH[vb1 + jo];
            short8 Bl1 = *(const short8*)&VL[vb1 + jo];
            oc0 = MFMA_BF16(Ap, Bh0, oc0, 0, 0, 0);
            oc0 = MFMA_BF16(Ap, Bl0, oc0, 0, 0, 0);
            oc1 = MFMA_BF16(Ap, Bh1, oc1, 0, 0, 0);
            oc1 = MFMA_BF16(Ap, Bl1, oc1, 0, 0, 0);
        }
        __syncthreads();          // packed fully consumed -> reuse SB as f32
        float* FS = (float*)SB;
        {   // each wave writes 16 rows x 32 d partials (lane-unique slots)
            #pragma unroll
            for (int g = 0; g < 4; ++g) {
                int row = quad * 4 + g;
                FS[wave * 512 + row * 32 + n16] = oc0[g];
                FS[wave * 512 + row * 32 + 16 + n16] = oc1[g];
            }
        }
    }
    __syncthreads();
    {
        float* FS = (float*)SB;
        int r2 = t >> 5, d = t & 31;
        float sum = 0.f;
        #pragma unroll
        for (int w = 0; w < 8; ++w)
            sum += FS[w * 512 + r2 * 32 + d];
        int ii = i0 + r2;
        O[base + (size_t)ii * DM + d] = sum * l2inv_s[r2];
    }
}

// ---------- small precompute: q3row = know@W3q+b3q; key8 = sigmoid heads ---
__global__ __launch_bounds__(256) void precompute_kernel(
    const float* __restrict__ know,
    const float* __restrict__ W3q, const float* __restrict__ b3q,
    const float* __restrict__ lkW, const float* __restrict__ lkb,
    float* __restrict__ q3row, float* __restrict__ key8)
{
    __shared__ float kn[DM];
    int t = threadIdx.x;
    kn[t] = know[t];
    __syncthreads();
    float acc = b3q[t];
    for (int c = 0; c < DM; ++c) acc += kn[c] * W3q[(size_t)c * DM + t];
    q3row[t] = acc;
    float bk = lkb[t];
    for (int h = 0; h < NH; ++h) {
        float a = bk;
        #pragma unroll
        for (int c = 0; c < DK; ++c) a += kn[h * DK + c] * lkW[(size_t)c * DM + t];
        key8[(size_t)h * DM + t] = 1.f / (1.f + __expf(-a));
    }
}

// ---------- final readout (f32 output), single-barrier beta reduction ------
__global__ __launch_bounds__(256) void readout_kernel(
    const float* __restrict__ h3, const float* __restrict__ qe,
    const float* __restrict__ key8,
    const float* __restrict__ lvW, const float* __restrict__ lvb,
    float* __restrict__ out)
{
    __shared__ float hrow[DM], qrow[DM];
    __shared__ float red8[4][NH];
    int n = blockIdx.x, t = threadIdx.x;
    int lane = t & 63, wid = t >> 6;
    hrow[t] = h3[(size_t)n * DM + t];
    qrow[t] = qe[(size_t)n * DM + t];
    __syncthreads();
    float ph[NH];
    #pragma unroll
    for (int h = 0; h < NH; ++h) {
        float v = key8[(size_t)h * DM + t] * qrow[t];
        v = waveRedSum(v);
        ph[h] = v;
    }
    if (lane == 0) {
        #pragma unroll
        for (int h = 0; h < NH; ++h) red8[wid][h] = ph[h];
    }
    __syncthreads();
    float beta[NH];
    #pragma unroll
    for (int h = 0; h < NH; ++h)
        beta[h] = red8[0][h] + red8[1][h] + red8[2][h] + red8[3][h];
    float bv = lvb[t];
    float vh[NH];
    for (int h = 0; h < NH; ++h) {
        float a = bv;
        #pragma unroll
        for (int c = 0; c < DK; ++c) a += hrow[h * DK + c] * lvW[(size_t)c * DM + t];
        vh[h] = 1.f / (1.f + __expf(-a));
    }
    float mb = beta[0];
    #pragma unroll
    for (int h = 1; h < NH; ++h) mb = fmaxf(mb, beta[h]);
    float se = 0.f, eh[NH];
    #pragma unroll
    for (int h = 0; h < NH; ++h) { eh[h] = __expf(beta[h] - mb); se += eh[h]; }
    float sinv = 1.f / se;
    float o = 0.f;
    #pragma unroll
    for (int h = 0; h < NH; ++h) o += eh[h] * sinv * vh[h];
    out[(size_t)n * DM + t] = o;
}

extern "C" void kernel_launch(void* const* d_in, const int* in_sizes, int n_in,
                              void* d_out, int out_size, void* d_ws, size_t ws_size,
                              hipStream_t stream) {
    (void)in_sizes; (void)n_in; (void)out_size; (void)ws_size;
    const float* q_emb  = (const float*)d_in[0];
    const float* qa_emb = (const float*)d_in[1];
    const float* b1_Wq = (const float*)d_in[2];
    const float* b1_bq = (const float*)d_in[3];
    const float* b1_Wv = (const float*)d_in[4];
    const float* b1_bv = (const float*)d_in[5];
    const float* b1_Wo = (const float*)d_in[6];
    const float* b1_bo = (const float*)d_in[7];
    const float* b1_gam = (const float*)d_in[8];
    const float* b1_lng = (const float*)d_in[9];
    const float* b1_lnb = (const float*)d_in[10];
    const float* b2_Wq = (const float*)d_in[11];
    const float* b2_bq = (const float*)d_in[12];
    const float* b2_Wv = (const float*)d_in[13];
    const float* b2_bv = (const float*)d_in[14];
    const float* b2_Wo = (const float*)d_in[15];
    const float* b2_bo = (const float*)d_in[16];
    const float* b2_gam = (const float*)d_in[17];
    const float* b2_lng = (const float*)d_in[18];
    const float* b2_lnb = (const float*)d_in[19];
    const float* b3_Wq = (const float*)d_in[20];
    const float* b3_bq = (const float*)d_in[21];
    const float* b3_Wk = (const float*)d_in[22];
    const float* b3_bk = (const float*)d_in[23];
    const float* b3_Wv = (const float*)d_in[24];
    const float* b3_bv = (const float*)d_in[25];
    const float* b3_Wo = (const float*)d_in[26];
    const float* b3_bo = (const float*)d_in[27];
    const float* b3_gam = (const float*)d_in[28];
    const float* b3_lng = (const float*)d_in[29];
    const float* b3_lnb = (const float*)d_in[30];
    const float* know  = (const float*)d_in[31];
    const float* lk_W  = (const float*)d_in[32];
    const float* lk_b  = (const float*)d_in[33];
    const float* lv_W  = (const float*)d_in[34];
    const float* lv_b  = (const float*)d_in[35];

    const size_t SLAB = (size_t)ROWS * DM;  // 1,048,576 floats = 4 MB
    const size_t USLAB = 2 * SLAB;          // split-bf16 buffer (hi+lo), ushorts
    float* A1 = (float*)d_ws;               // q1k1 f32; later k3
    float* A2 = A1 + SLAB;                  // q2k2 f32
    float* C1 = A2 + SLAB;                  // att1 out; later att3 out
    float* C2 = C1 + SLAB;                  // att2 out; later h3
    unsigned short* KS1 = (unsigned short*)(C2 + SLAB);  // later hq (f32)
    unsigned short* KS2 = KS1 + USLAB;                   // later ha (f32)
    unsigned short* VS1 = KS2 + USLAB;                   // later VS3
    unsigned short* VS2 = VS1 + USLAB;
    float* q3row = (float*)(VS2 + USLAB);   // 256
    float* key8  = q3row + DM;              // 8*256
    unsigned short* Wsp = (unsigned short*)(key8 + NH * DM);  // 9 x 256KB
    float* hq = (float*)KS1;
    float* ha = (float*)KS2;
    float* k3 = A1;
    unsigned short* VS3 = VS1;
    float* O3 = C1;
    float* h3 = C2;

    auto WH = [&](int i) { return Wsp + (size_t)i * 131072; };
    // 0:b1_Wq 1:b1_Wv 2:b1_Wo 3:b2_Wq 4:b2_Wv 5:b2_Wo 6:b3_Wk 7:b3_Wv 8:b3_Wo

    dim3 blk(256);
    dim3 ablk(512);
    dim3 agrid2(SEQ / RT, 32);        // dual-set attention (128 x 32)
    dim3 agrid1(SEQ / RT, 16);        // single-set attention
    dim3 rgrid(ROWS);

    convert_w_kernel<<<dim3(64, 9), blk, 0, stream>>>(
        b1_Wq, b1_Wv, b1_Wo, b2_Wq, b2_Wv, b2_Wo, b3_Wk, b3_Wv, b3_Wo, Wsp);

    precompute_kernel<<<dim3(1), blk, 0, stream>>>(know, b3_Wq, b3_bq, lk_W, lk_b, q3row, key8);

    // ---- blocks 1+2 projections: q/k f32+rowsplit, v transposed-split ----
    gemm4_kernel<<<dim3(ROWS/16, 4), blk, 0, stream>>>(
        q_emb,  WH(0), b1_bq, A1,      KS1,     nullptr,
        q_emb,  WH(1), b1_bv, nullptr, nullptr, VS1,
        qa_emb, WH(3), b2_bq, A2,      KS2,     nullptr,
        qa_emb, WH(4), b2_bv, nullptr, nullptr, VS2);

    // ---- blocks 1+2 attention (one dual-set launch) ----
    attn_tile_kernel<<<agrid2, ablk, 0, stream>>>(
        A1, nullptr, KS1, VS1, b1_gam, C1,
        A2, nullptr, KS2, VS2, b2_gam, C2, 1, 0);

    // ---- output projections + residual + LN (fused) -> hq, ha ----
    gemm_ln2_kernel<<<dim3(ROWS/16, 2), blk, 0, stream>>>(
        C1, WH(2), b1_bo, q_emb,  b1_lng, b1_lnb, hq, 0,
        C2, WH(5), b2_bo, qa_emb, b2_lng, b2_lnb, ha, 0);

    // ---- block 3: k3 = hq@W3k (f32), v3 = ha@W3v (transposed split) ----
    gemm4_kernel<<<dim3(ROWS/16, 2), blk, 0, stream>>>(
        hq, WH(6), b3_bk, k3,      nullptr, nullptr,
        ha, WH(7), b3_bv, nullptr, nullptr, VS3,
        hq, WH(6), b3_bk, k3,      nullptr, nullptr,   // unused sets
        hq, WH(6), b3_bk, k3,      nullptr, nullptr);

    attn_tile_kernel<<<agrid1, ablk, 0, stream>>>(
        q3row, k3, nullptr, VS3, b3_gam, O3,
        q3row, k3, nullptr, VS3, b3_gam, O3, 0, 1);

    // ---- y3 + know-residual + LN (fused) -> h3 ----
    gemm_ln2_kernel<<<dim3(ROWS/16, 1), blk, 0, stream>>>(
        O3, WH(8), b3_bo, know, b3_lng, b3_lnb, h3, 1,
        O3, WH(8), b3_bo, know, b3_lng, b3_lnb, h3, 1);

    readout_kernel<<<rgrid, blk, 0, stream>>>(h3, q_emb, key8, lv_W, lv_b,
                                              (float*)d_out);
}

// Round 25
// 596.021 us; speedup vs baseline: 1.0675x; 1.0632x over previous
//
#include <hip/hip_runtime.h>
#include <hip/hip_bf16.h>

#define DM 256
#define NH 8
#define DK 32
#define BSZ 2
#define SEQ 2048
#define ROWS (BSZ*SEQ)   // 4096
#define RT 16            // query rows per attention tile (full MFMA rows)
#define SRB 2312         // ushort row stride; swizzle phys = j + 8*(j>>6), max 2295

static __device__ __forceinline__ int sw8(int j) { return j + ((j >> 6) << 3); }

typedef __attribute__((ext_vector_type(8))) short short8;
typedef __attribute__((ext_vector_type(4))) float f32x4;

// f32 -> bf16 bits, round-to-nearest-even (validated r15)
static __device__ __forceinline__ unsigned short f2bf(float f) {
    unsigned u = __float_as_uint(f);
    return (unsigned short)((u + 0x7FFFu + ((u >> 16) & 1u)) >> 16);
}
static __device__ __forceinline__ float bf2f(unsigned short h) {
    return __uint_as_float(((unsigned)h) << 16);
}

#define MFMA_BF16 __builtin_amdgcn_mfma_f32_16x16x32_bf16
#define LOG2E 1.44269504088896340736f

// ---------- reduction helpers ----------
static __device__ __forceinline__ float waveRedSum(float v) {
    #pragma unroll
    for (int off = 32; off > 0; off >>= 1) v += __shfl_down(v, off, 64);
    return v;
}

// ---------- one-time: weights -> split-bf16, transposed [n][k] ----------
__global__ __launch_bounds__(256) void convert_w_kernel(
    const float* __restrict__ S0, const float* __restrict__ S1, const float* __restrict__ S2,
    const float* __restrict__ S3, const float* __restrict__ S4, const float* __restrict__ S5,
    const float* __restrict__ S6, const float* __restrict__ S7, const float* __restrict__ S8,
    unsigned short* __restrict__ dst)
{
    const float* W;
    int s = blockIdx.y;
    if (s == 0) W = S0; else if (s == 1) W = S1; else if (s == 2) W = S2;
    else if (s == 3) W = S3; else if (s == 4) W = S4; else if (s == 5) W = S5;
    else if (s == 6) W = S6; else if (s == 7) W = S7; else W = S8;
    unsigned short* H = dst + (size_t)s * 131072;
    unsigned short* L = H + 65536;

    int e = blockIdx.x * 1024 + threadIdx.x * 4;
    int k = e >> 8, n = e & 255;
    float4 w4 = *(const float4*)(W + e);
    float v[4] = {w4.x, w4.y, w4.z, w4.w};
    #pragma unroll
    for (int i = 0; i < 4; ++i) {
        unsigned short h = f2bf(v[i]);
        H[(size_t)(n + i) * 256 + k] = h;
        L[(size_t)(n + i) * 256 + k] = (unsigned short)f2bf(v[i] - bf2f(h));
    }
}

// ---------- batched MFMA GEMM (16x256/block, 4 sets) with optional ----------
// split-bf16 side outputs: KSo = [row][col] hi/lo; VSo = [col][row] hi/lo.
__global__ __launch_bounds__(256) void gemm4_kernel(
    const float* __restrict__ X0, const unsigned short* __restrict__ H0, const float* __restrict__ B0,
    float* __restrict__ Y0, unsigned short* __restrict__ K0o, unsigned short* __restrict__ V0o,
    const float* __restrict__ X1, const unsigned short* __restrict__ H1, const float* __restrict__ B1,
    float* __restrict__ Y1, unsigned short* __restrict__ K1o, unsigned short* __restrict__ V1o,
    const float* __restrict__ X2, const unsigned short* __restrict__ H2, const float* __restrict__ B2,
    float* __restrict__ Y2, unsigned short* __restrict__ K2o, unsigned short* __restrict__ V2o,
    const float* __restrict__ X3, const unsigned short* __restrict__ H3, const float* __restrict__ B3,
    float* __restrict__ Y3, unsigned short* __restrict__ K3o, unsigned short* __restrict__ V3o)
{
    const float *X, *Bias; const unsigned short* H; float* Yf;
    unsigned short *KSo, *VSo;
    int s = blockIdx.y;
    if (s == 0)      { X = X0; H = H0; Bias = B0; Yf = Y0; KSo = K0o; VSo = V0o; }
    else if (s == 1) { X = X1; H = H1; Bias = B1; Yf = Y1; KSo = K1o; VSo = V1o; }
    else if (s == 2) { X = X2; H = H2; Bias = B2; Yf = Y2; KSo = K2o; VSo = V2o; }
    else             { X = X3; H = H3; Bias = B3; Yf = Y3; KSo = K3o; VSo = V3o; }
    const unsigned short* L = H + 65536;

    __shared__ __align__(16) unsigned short XhL[16 * 264];
    __shared__ __align__(16) unsigned short XlL[16 * 264];
    int t = threadIdx.x;
    int r0 = blockIdx.x * 16;
    {   // stage X tile as split bf16
        int r = t >> 4, c0 = (t & 15) * 16;
        const float* xp = X + (size_t)(r0 + r) * DM + c0;
        #pragma unroll
        for (int i = 0; i < 16; i += 4) {
            float4 v4 = *(const float4*)(xp + i);
            float vv[4] = {v4.x, v4.y, v4.z, v4.w};
            #pragma unroll
            for (int j = 0; j < 4; ++j) {
                unsigned short h = f2bf(vv[j]);
                XhL[r * 264 + c0 + i + j] = h;
                XlL[r * 264 + c0 + i + j] = (unsigned short)f2bf(vv[j] - bf2f(h));
            }
        }
    }
    __syncthreads();
    int lane = t & 63, wv = t >> 6;
    int m = lane & 15, quad = lane >> 4;
    f32x4 aa[4];
    #pragma unroll
    for (int nt = 0; nt < 4; ++nt) { aa[nt][0]=0.f; aa[nt][1]=0.f; aa[nt][2]=0.f; aa[nt][3]=0.f; }
    #pragma unroll 1
    for (int kc = 0; kc < 8; ++kc) {
        int k0 = kc * 32;
        short8 Ah = *(const short8*)&XhL[m * 264 + k0 + quad * 8];
        short8 Al = *(const short8*)&XlL[m * 264 + k0 + quad * 8];
        size_t boff = (size_t)(wv * 64 + m) * 256 + k0 + quad * 8;
        #pragma unroll
        for (int nt = 0; nt < 4; ++nt) {
            short8 Bh = *(const short8*)(H + boff + nt * 16 * 256);
            short8 Bl = *(const short8*)(L + boff + nt * 16 * 256);
            aa[nt] = MFMA_BF16(Al, Bh, aa[nt], 0, 0, 0);
            aa[nt] = MFMA_BF16(Ah, Bl, aa[nt], 0, 0, 0);
            aa[nt] = MFMA_BF16(Ah, Bh, aa[nt], 0, 0, 0);
        }
    }
    // epilogue: D col = lane&15 (+16*nt +64*wv), row = quad*4+g
    int col0 = wv * 64 + m;
    #pragma unroll
    for (int nt = 0; nt < 4; ++nt) {
        int col = col0 + nt * 16;
        float bb = Bias[col];
        float yv[4];
        #pragma unroll
        for (int g = 0; g < 4; ++g) yv[g] = aa[nt][g] + bb;
        if (Yf) {
            #pragma unroll
            for (int g = 0; g < 4; ++g)
                Yf[(size_t)(r0 + quad * 4 + g) * DM + col] = yv[g];
        }
        if (KSo) {
            unsigned short* KH = KSo;
            unsigned short* KL = KSo + (size_t)ROWS * DM;
            #pragma unroll
            for (int g = 0; g < 4; ++g) {
                unsigned short hb = f2bf(yv[g]);
                KH[(size_t)(r0 + quad * 4 + g) * DM + col] = hb;
                KL[(size_t)(r0 + quad * 4 + g) * DM + col] =
                    (unsigned short)f2bf(yv[g] - bf2f(hb));
            }
        }
        if (VSo) {
            unsigned short* VH = VSo;
            unsigned short* VL = VSo + (size_t)ROWS * DM;
            ushort4 h4, l4;
            unsigned short hb;
            hb = f2bf(yv[0]); h4.x = hb; l4.x = (unsigned short)f2bf(yv[0] - bf2f(hb));
            hb = f2bf(yv[1]); h4.y = hb; l4.y = (unsigned short)f2bf(yv[1] - bf2f(hb));
            hb = f2bf(yv[2]); h4.z = hb; l4.z = (unsigned short)f2bf(yv[2] - bf2f(hb));
            hb = f2bf(yv[3]); h4.w = hb; l4.w = (unsigned short)f2bf(yv[3] - bf2f(hb));
            *(ushort4*)&VH[(size_t)col * ROWS + r0 + quad * 4] = h4;
            *(ushort4*)&VL[(size_t)col * ROWS + r0 + quad * 4] = l4;
        }
    }
}

// ---------- MFMA GEMM + residual + LayerNorm fused (2 sets) ----------
__global__ __launch_bounds__(256) void gemm_ln2_kernel(
    const float* __restrict__ X0, const unsigned short* __restrict__ H0, const float* __restrict__ B0,
    const float* __restrict__ R0, const float* __restrict__ G0, const float* __restrict__ L0,
    float* __restrict__ Y0, int bc0,
    const float* __restrict__ X1, const unsigned short* __restrict__ H1, const float* __restrict__ B1,
    const float* __restrict__ R1, const float* __restrict__ G1, const float* __restrict__ L1,
    float* __restrict__ Y1, int bc1)
{
    const float *X, *Bias, *R, *G, *Lb; const unsigned short* H; float* Y; int bc;
    if (blockIdx.y == 0) { X=X0; H=H0; Bias=B0; R=R0; G=G0; Lb=L0; Y=Y0; bc=bc0; }
    else                 { X=X1; H=H1; Bias=B1; R=R1; G=G1; Lb=L1; Y=Y1; bc=bc1; }
    const unsigned short* L = H + 65536;

    __shared__ __align__(16) unsigned short XhL[16 * 264];
    __shared__ __align__(16) unsigned short XlL[16 * 264];
    __shared__ __align__(16) float yl[16 * 260];
    int t = threadIdx.x;
    int r0 = blockIdx.x * 16;
    {   int r = t >> 4, c0 = (t & 15) * 16;
        const float* xp = X + (size_t)(r0 + r) * DM + c0;
        #pragma unroll
        for (int i = 0; i < 16; i += 4) {
            float4 v4 = *(const float4*)(xp + i);
            float vv[4] = {v4.x, v4.y, v4.z, v4.w};
            #pragma unroll
            for (int j = 0; j < 4; ++j) {
                unsigned short h = f2bf(vv[j]);
                XhL[r * 264 + c0 + i + j] = h;
                XlL[r * 264 + c0 + i + j] = (unsigned short)f2bf(vv[j] - bf2f(h));
            }
        }
    }
    __syncthreads();
    int lane = t & 63, wv = t >> 6;
    int m = lane & 15, quad = lane >> 4;
    f32x4 aa[4];
    #pragma unroll
    for (int nt = 0; nt < 4; ++nt) { aa[nt][0]=0.f; aa[nt][1]=0.f; aa[nt][2]=0.f; aa[nt][3]=0.f; }
    #pragma unroll 1
    for (int kc = 0; kc < 8; ++kc) {
        int k0 = kc * 32;
        short8 Ah = *(const short8*)&XhL[m * 264 + k0 + quad * 8];
        short8 Al = *(const short8*)&XlL[m * 264 + k0 + quad * 8];
        size_t boff = (size_t)(wv * 64 + m) * 256 + k0 + quad * 8;
        #pragma unroll
        for (int nt = 0; nt < 4; ++nt) {
            short8 Bh = *(const short8*)(H + boff + nt * 16 * 256);
            short8 Bl = *(const short8*)(L + boff + nt * 16 * 256);
            aa[nt] = MFMA_BF16(Al, Bh, aa[nt], 0, 0, 0);
            aa[nt] = MFMA_BF16(Ah, Bl, aa[nt], 0, 0, 0);
            aa[nt] = MFMA_BF16(Ah, Bh, aa[nt], 0, 0, 0);
        }
    }
    {
        int col0 = wv * 64 + m;
        #pragma unroll
        for (int nt = 0; nt < 4; ++nt) {
            int col = col0 + nt * 16;
            float bb = Bias[col];
            #pragma unroll
            for (int g = 0; g < 4; ++g) {
                int row = quad * 4 + g;
                float res = bc ? R[col] : R[(size_t)(r0 + row) * DM + col];
                yl[row * 260 + col] = aa[nt][g] + bb + res;
            }
        }
    }
    __syncthreads();
    {
        int r = t >> 4, c0 = (t & 15) * 16;
        float vals[16];
        float part = 0.f;
        #pragma unroll
        for (int i = 0; i < 16; ++i) { vals[i] = yl[r * 260 + c0 + i]; part += vals[i]; }
        #pragma unroll
        for (int off = 8; off; off >>= 1) part += __shfl_xor(part, off, 16);
        float mean = part * (1.f / DM);
        float vp = 0.f;
        #pragma unroll
        for (int i = 0; i < 16; ++i) { float d = vals[i] - mean; vp += d * d; }
        #pragma unroll
        for (int off = 8; off; off >>= 1) vp += __shfl_xor(vp, off, 16);
        float rs = rsqrtf(vp * (1.f / DM) + 1e-5f);
        float* yp = Y + (size_t)(r0 + r) * DM + c0;
        #pragma unroll
        for (int i = 0; i < 16; i += 4) {
            float4 o;
            o.x = (vals[i+0] - mean) * rs * G[c0+i+0] + Lb[c0+i+0];
            o.y = (vals[i+1] - mean) * rs * G[c0+i+1] + Lb[c0+i+1];
            o.z = (vals[i+2] - mean) * rs * G[c0+i+2] + Lb[c0+i+2];
            o.w = (vals[i+3] - mean) * rs * G[c0+i+3] + Lb[c0+i+3];
            *(float4*)(yp + i) = o;
        }
    }
}

// ---------- attn3 shared scores + inclusive exp2 scan, one block per bh ----
__global__ __launch_bounds__(256) void score3_kernel(
    const float* __restrict__ q3row, const float* __restrict__ K3,
    unsigned short* __restrict__ S3, float* __restrict__ C3)
{
    __shared__ float wsum[4];
    int bh = blockIdx.x;           // b*8+h
    int b = bh >> 3, h = bh & 7;
    int t = threadIdx.x;
    int lane = t & 63, wv = t >> 6;
    const float scaleL2 = 0.17677669529663687f * LOG2E;
    float q[DK];
    #pragma unroll
    for (int d = 0; d < DK; ++d) q[d] = q3row[h * DK + d] * scaleL2;
    size_t kb = ((size_t)b * SEQ) * DM + h * DK;
    float einc[8];
    unsigned short sb[8];
    float run = 0.f;
    #pragma unroll 1
    for (int k = 0; k < 8; ++k) {
        int j = t * 8 + k;
        const float* kp = K3 + kb + (size_t)j * DM;
        float s = 0.f;
        #pragma unroll
        for (int d = 0; d < DK; ++d) s += q[d] * kp[d];
        unsigned short sb16 = f2bf(s);
        sb[k] = sb16;
        run += exp2f(bf2f(sb16));
        einc[k] = run;                 // inclusive within thread
    }
    // exclusive prefix of per-thread totals across 256 threads
    float x = run;
    #pragma unroll
    for (int off = 1; off < 64; off <<= 1) {
        float y = __shfl_up(x, off, 64);
        if (lane >= off) x += y;
    }
    if (lane == 63) wsum[wv] = x;
    __syncthreads();
    float woff = 0.f;
    for (int w = 0; w < wv; ++w) woff += wsum[w];
    float pre = woff + x - run;
    #pragma unroll
    for (int k = 0; k < 8; ++k) {
        int j = t * 8 + k;
        S3[(size_t)bh * SEQ + j] = sb[k];
        C3[(size_t)bh * SEQ + j] = pre + einc[k];
    }
}

// ---------- tiled attention with distance-decay bias ----------
// RT=16 + 512 threads. MFMA path (blocks 1/2): phase 1 + fused row sums +
// mask-free pass C (r24). qbcast path (attn3): phases 1/B/scan replaced by
// precomputed shared scores S3 and inclusive scan C3 (per bh) — pass C
// computes p directly from prefix ratios; phase 5 unchanged.
__global__ __launch_bounds__(512) void attn_tile_kernel(
    const float* __restrict__ Q0,
    const unsigned short* __restrict__ KS0, const unsigned short* __restrict__ VS0,
    const float* __restrict__ g0, float* __restrict__ O0,
    const float* __restrict__ Q1,
    const unsigned short* __restrict__ KS1, const unsigned short* __restrict__ VS1,
    const float* __restrict__ g1, float* __restrict__ O1,
    const unsigned short* __restrict__ S3g, const float* __restrict__ C3g,
    int peek, int qbcast)
{
    __shared__ __align__(16) unsigned short SB[RT * SRB];
    __shared__ float qs[RT][DK];
    __shared__ float l2inv_s[RT];
    __shared__ float rowsum[8 * RT];   // per-wave partial l (MFMA path)

    int y = blockIdx.y;
    int set = y >> 4, bh = y & 15;
    const float* Q = set ? Q1 : Q0;
    const unsigned short* KS = set ? KS1 : KS0;
    const unsigned short* VS = set ? VS1 : VS0;
    const float* gm = set ? g1 : g0;
    float* O = set ? O1 : O0;

    int b = bh >> 3, h = bh & 7;
    int i0 = ((int)gridDim.x - 1 - (int)blockIdx.x) * RT;   // largest-first
    int t = threadIdx.x;
    size_t base = ((size_t)b * SEQ) * DM + (size_t)h * DK;

    int njAll = peek ? (i0 + RT) : (i0 + RT - 1);  // >= 15 always
    int njPad32 = (njAll + 31) & ~31;
    int njPad128 = (njAll + 127) & ~127;           // pass-C extent
    const float scaleL2 = 0.17677669529663687f * LOG2E;   // 1/sqrt(32)*log2e

    if (!qbcast) {
        {   // load Q tile (512 threads = 16 rows x 32)
            int r = t >> 5, d = t & 31;
            qs[r][d] = Q[base + (size_t)(i0 + r) * DM + d];
        }
        __syncthreads();

        // ---- Phase 1: MFMA scores + fused per-row exp2 partial sums.
        {
            int wave = t >> 6, lane = t & 63;
            int m = lane & 15, quad = lane >> 4;

            float av[8];
            {
                float4 qa = *(const float4*)&qs[m][8 * quad];
                float4 qb = *(const float4*)&qs[m][8 * quad + 4];
                av[0]=qa.x*scaleL2; av[1]=qa.y*scaleL2; av[2]=qa.z*scaleL2; av[3]=qa.w*scaleL2;
                av[4]=qb.x*scaleL2; av[5]=qb.y*scaleL2; av[6]=qb.z*scaleL2; av[7]=qb.w*scaleL2;
            }
            short8 Ah, Al;
            #pragma unroll
            for (int i = 0; i < 8; ++i) {
                unsigned short hb = f2bf(av[i]);
                Ah[i] = (short)hb;
                Al[i] = (short)f2bf(av[i] - bf2f(hb));
            }

            const unsigned short* KH = KS;
            const unsigned short* KL = KS + (size_t)ROWS * DM;
            size_t rowb = (size_t)b * SEQ;
            int njr0 = i0 + quad * 4 + peek;      // nj of row quad*4
            float rp0 = 0.f, rp1 = 0.f, rp2 = 0.f, rp3 = 0.f;
            int nChunks = (njAll + 15) >> 4;
            #pragma unroll 1
            for (int c = wave; c < nChunks; c += 8) {
                int j0 = c << 4;
                size_t off = (rowb + j0 + m) * DM + h * DK + quad * 8;
                short8 Bh = *(const short8*)&KH[off];
                short8 Bl = *(const short8*)&KL[off];
                f32x4 acc = {0.f, 0.f, 0.f, 0.f};
                acc = MFMA_BF16(Ah, Bl, acc, 0, 0, 0);
                acc = MFMA_BF16(Al, Bh, acc, 0, 0, 0);
                acc = MFMA_BF16(Ah, Bh, acc, 0, 0, 0);
                int jcol = j0 + m;
                int sj = sw8(jcol);
                #pragma unroll
                for (int g = 0; g < 4; ++g)
                    SB[(quad * 4 + g) * SRB + sj] = f2bf(acc[g]);
                rp0 += (jcol < njr0 + 0) ? exp2f(acc[0]) : 0.f;
                rp1 += (jcol < njr0 + 1) ? exp2f(acc[1]) : 0.f;
                rp2 += (jcol < njr0 + 2) ? exp2f(acc[2]) : 0.f;
                rp3 += (jcol < njr0 + 3) ? exp2f(acc[3]) : 0.f;
            }
            #pragma unroll
            for (int off = 1; off < 16; off <<= 1) {
                rp0 += __shfl_xor(rp0, off, 64);
                rp1 += __shfl_xor(rp1, off, 64);
                rp2 += __shfl_xor(rp2, off, 64);
                rp3 += __shfl_xor(rp3, off, 64);
            }
            if (m == 0) {
                rowsum[wave * RT + quad * 4 + 0] = rp0;
                rowsum[wave * RT + quad * 4 + 1] = rp1;
                rowsum[wave * RT + quad * 4 + 2] = rp2;
                rowsum[wave * RT + quad * 4 + 3] = rp3;
            }
        }
        __syncthreads();

        // ---- Tail fill: bf16 -inf into [nj_r, njPad128) per row ----
        {
            int r = t >> 5, c = t & 31;
            int i = i0 + r;
            int nj = peek ? (i + 1) : i;
            for (int j = nj + c; j < njPad128; j += 32)
                SB[r * SRB + sw8(j)] = 0xFF80u;   // bf16 -inf
        }
        __syncthreads();
    }

    // ---- Pass C ----
    if (qbcast) {
        // attn3: p from precomputed shared scores + prefix scan (no phase 1,
        // no pass B, no serial scan). SB written for all j < njPad128.
        int r = t >> 5, c = t & 31;
        int i = i0 + r;
        int nj = peek ? (i + 1) : i;
        unsigned short* Sr = SB + r * SRB;
        float gamma2 = -log1pf(__expf(gm[h])) * LOG2E;
        const unsigned short* s3p = S3g + (size_t)bh * SEQ;
        const float* c3p = C3g + (size_t)bh * SEQ;
        float linv = (nj > 0) ? 1.f / c3p[nj - 1] : 0.f;
        float l2 = 0.f;
        #pragma unroll 1
        for (int k = 0; 128 * k < njPad32; ++k) {
            int j4 = 128 * k + 4 * c;          // <= njPad128-4 <= 2044
            ushort4 su = *(const ushort4*)&s3p[j4];
            float4 C4 = *(const float4*)&c3p[j4];
            float pb = (float)(i - j4);
            float4 p;
            { float dist = sqrtf(fmaxf((1.f - C4.x * linv) * pb, 0.f));
              float eff = fmaxf(exp2f(dist * gamma2), 1e-5f);
              p.x = (j4 + 0 < nj) ? exp2f(bf2f(su.x) * eff) : 0.f; l2 += p.x; }
            { float dist = sqrtf(fmaxf((1.f - C4.y * linv) * (pb - 1.f), 0.f));
              float eff = fmaxf(exp2f(dist * gamma2), 1e-5f);
              p.y = (j4 + 1 < nj) ? exp2f(bf2f(su.y) * eff) : 0.f; l2 += p.y; }
            { float dist = sqrtf(fmaxf((1.f - C4.z * linv) * (pb - 2.f), 0.f));
              float eff = fmaxf(exp2f(dist * gamma2), 1e-5f);
              p.z = (j4 + 2 < nj) ? exp2f(bf2f(su.z) * eff) : 0.f; l2 += p.z; }
            { float dist = sqrtf(fmaxf((1.f - C4.w * linv) * (pb - 3.f), 0.f));
              float eff = fmaxf(exp2f(dist * gamma2), 1e-5f);
              p.w = (j4 + 3 < nj) ? exp2f(bf2f(su.w) * eff) : 0.f; l2 += p.w; }
            ushort4 pk;
            pk.x = f2bf(p.x); pk.y = f2bf(p.y); pk.z = f2bf(p.z); pk.w = f2bf(p.w);
            *(ushort4*)&Sr[sw8(j4)] = pk;
        }
        #pragma unroll
        for (int off = 16; off; off >>= 1) l2 += __shfl_xor(l2, off, 32);
        if (c == 0) l2inv_s[r] = (nj > 0) ? (1.f / l2) : 0.f;
    } else {
        int r = t >> 5, c = t & 31;
        int i = i0 + r;
        int nj = peek ? (i + 1) : i;
        unsigned short* Sr = SB + r * SRB;
        float gamma2 = -log1pf(__expf(gm[h])) * LOG2E;

        float l = 0.f;
        #pragma unroll
        for (int w = 0; w < 8; ++w) l += rowsum[w * RT + r];
        float linv = 1.f / l;

        float l2 = 0.f;
        float Bc = 0.f;
        #pragma unroll 1
        for (int k = 0; 128 * k < njPad32; ++k) {
            int j4 = 128 * k + 4 * c;
            uint2 u = *(const uint2*)&Sr[sw8(j4)];
            float4 s4;
            s4.x = bf2f((unsigned short)u.x);
            s4.y = bf2f((unsigned short)(u.x >> 16));
            s4.z = bf2f((unsigned short)u.y);
            s4.w = bf2f((unsigned short)(u.y >> 16));
            float e0 = exp2f(s4.x) * linv;
            float e1 = exp2f(s4.y) * linv;
            float e2 = exp2f(s4.z) * linv;
            float e3 = exp2f(s4.w) * linv;
            float sig = e0 + e1 + e2 + e3;
            float x = sig;
            #pragma unroll
            for (int off = 1; off < 32; off <<= 1) {
                float yv = __shfl_up(x, off, 32);
                if (c >= off) x += yv;
            }
            float tot = __shfl(x, 31, 32);
            float cum = Bc + (x - sig);
            Bc += tot;
            float pb = (float)(i - j4);
            float4 p;
            cum += e0;
            { float dist = sqrtf(fmaxf((1.f - cum) * pb, 0.f));
              float eff = fmaxf(exp2f(dist * gamma2), 1e-5f);
              p.x = exp2f(s4.x * eff); l2 += p.x; }
            cum += e1;
            { float dist = sqrtf(fmaxf((1.f - cum) * (pb - 1.f), 0.f));
              float eff = fmaxf(exp2f(dist * gamma2), 1e-5f);
              p.y = exp2f(s4.y * eff); l2 += p.y; }
            cum += e2;
            { float dist = sqrtf(fmaxf((1.f - cum) * (pb - 2.f), 0.f));
              float eff = fmaxf(exp2f(dist * gamma2), 1e-5f);
              p.z = exp2f(s4.z * eff); l2 += p.z; }
            cum += e3;
            { float dist = sqrtf(fmaxf((1.f - cum) * (pb - 3.f), 0.f));
              float eff = fmaxf(exp2f(dist * gamma2), 1e-5f);
              p.w = exp2f(s4.w * eff); l2 += p.w; }
            ushort4 pk;
            pk.x = f2bf(p.x); pk.y = f2bf(p.y); pk.z = f2bf(p.z); pk.w = f2bf(p.w);
            *(ushort4*)&Sr[sw8(j4)] = pk;
        }
        #pragma unroll
        for (int off = 16; off; off >>= 1) l2 += __shfl_xor(l2, off, 32);
        if (c == 0) l2inv_s[r] = (nj > 0) ? (1.f / l2) : 0.f;
    }
    __syncthreads();

    // ---- Phase 5 PV: MFMA, P bf16 in SB (A, 16 rows all used), split V (B).
    {
        int wave = t >> 6, lane = t & 63;
        int n16 = lane & 15, quad = lane >> 4;
        const unsigned short* VH = VS;
        const unsigned short* VL = VS + (size_t)ROWS * DM;
        size_t vb0 = (size_t)(h * DK + n16) * ROWS + (size_t)b * SEQ;
        size_t vb1 = (size_t)(h * DK + 16 + n16) * ROWS + (size_t)b * SEQ;
        f32x4 oc0 = {0.f,0.f,0.f,0.f}, oc1 = {0.f,0.f,0.f,0.f};
        #pragma unroll 1
        for (int j0 = wave * 32; j0 < njPad32; j0 += 256) {
            short8 Ap = *(const short8*)&SB[n16 * SRB + sw8(j0 + quad * 8)];
            int jo = j0 + quad * 8;
            short8 Bh0 = *(const short8*)&VH[vb0 + jo];
            short8 Bl0 = *(const short8*)&VL[vb0 + jo];
            short8 Bh1 = *(const short8*)&VH[vb1 + jo];
            short8 Bl1 = *(const short8*)&VL[vb1 + jo];
            oc0 = MFMA_BF16(Ap, Bh0, oc0, 0, 0, 0);
            oc0 = MFMA_BF16(Ap, Bl0, oc0, 0, 0, 0);
            oc1 = MFMA_BF16(Ap, Bh1, oc1, 0, 0, 0);
            oc1 = MFMA_BF16(Ap, Bl1, oc1, 0, 0, 0);
        }
        __syncthreads();          // packed fully consumed -> reuse SB as f32
        float* FS = (float*)SB;
        {
            #pragma unroll
            for (int g = 0; g < 4; ++g) {
                int row = quad * 4 + g;
                FS[wave * 512 + row * 32 + n16] = oc0[g];
                FS[wave * 512 + row * 32 + 16 + n16] = oc1[g];
            }
        }
    }
    __syncthreads();
    {
        float* FS = (float*)SB;
        int r2 = t >> 5, d = t & 31;
        float sum = 0.f;
        #pragma unroll
        for (int w = 0; w < 8; ++w)
            sum += FS[w * 512 + r2 * 32 + d];
        int ii = i0 + r2;
        O[base + (size_t)ii * DM + d] = sum * l2inv_s[r2];
    }
}

// ---------- small precompute: q3row = know@W3q+b3q; key8 = sigmoid heads ---
__global__ __launch_bounds__(256) void precompute_kernel(
    const float* __restrict__ know,
    const float* __restrict__ W3q, const float* __restrict__ b3q,
    const float* __restrict__ lkW, const float* __restrict__ lkb,
    float* __restrict__ q3row, float* __restrict__ key8)
{
    __shared__ float kn[DM];
    int t = threadIdx.x;
    kn[t] = know[t];
    __syncthreads();
    float acc = b3q[t];
    for (int c = 0; c < DM; ++c) acc += kn[c] * W3q[(size_t)c * DM + t];
    q3row[t] = acc;
    float bk = lkb[t];
    for (int h = 0; h < NH; ++h) {
        float a = bk;
        #pragma unroll
        for (int c = 0; c < DK; ++c) a += kn[h * DK + c] * lkW[(size_t)c * DM + t];
        key8[(size_t)h * DM + t] = 1.f / (1.f + __expf(-a));
    }
}

// ---------- final readout (f32 output), single-barrier beta reduction ------
__global__ __launch_bounds__(256) void readout_kernel(
    const float* __restrict__ h3, const float* __restrict__ qe,
    const float* __restrict__ key8,
    const float* __restrict__ lvW, const float* __restrict__ lvb,
    float* __restrict__ out)
{
    __shared__ float hrow[DM], qrow[DM];
    __shared__ float red8[4][NH];
    int n = blockIdx.x, t = threadIdx.x;
    int lane = t & 63, wid = t >> 6;
    hrow[t] = h3[(size_t)n * DM + t];
    qrow[t] = qe[(size_t)n * DM + t];
    __syncthreads();
    float ph[NH];
    #pragma unroll
    for (int h = 0; h < NH; ++h) {
        float v = key8[(size_t)h * DM + t] * qrow[t];
        v = waveRedSum(v);
        ph[h] = v;
    }
    if (lane == 0) {
        #pragma unroll
        for (int h = 0; h < NH; ++h) red8[wid][h] = ph[h];
    }
    __syncthreads();
    float beta[NH];
    #pragma unroll
    for (int h = 0; h < NH; ++h)
        beta[h] = red8[0][h] + red8[1][h] + red8[2][h] + red8[3][h];
    float bv = lvb[t];
    float vh[NH];
    for (int h = 0; h < NH; ++h) {
        float a = bv;
        #pragma unroll
        for (int c = 0; c < DK; ++c) a += hrow[h * DK + c] * lvW[(size_t)c * DM + t];
        vh[h] = 1.f / (1.f + __expf(-a));
    }
    float mb = beta[0];
    #pragma unroll
    for (int h = 1; h < NH; ++h) mb = fmaxf(mb, beta[h]);
    float se = 0.f, eh[NH];
    #pragma unroll
    for (int h = 0; h < NH; ++h) { eh[h] = __expf(beta[h] - mb); se += eh[h]; }
    float sinv = 1.f / se;
    float o = 0.f;
    #pragma unroll
    for (int h = 0; h < NH; ++h) o += eh[h] * sinv * vh[h];
    out[(size_t)n * DM + t] = o;
}

extern "C" void kernel_launch(void* const* d_in, const int* in_sizes, int n_in,
                              void* d_out, int out_size, void* d_ws, size_t ws_size,
                              hipStream_t stream) {
    (void)in_sizes; (void)n_in; (void)out_size; (void)ws_size;
    const float* q_emb  = (const float*)d_in[0];
    const float* qa_emb = (const float*)d_in[1];
    const float* b1_Wq = (const float*)d_in[2];
    const float* b1_bq = (const float*)d_in[3];
    const float* b1_Wv = (const float*)d_in[4];
    const float* b1_bv = (const float*)d_in[5];
    const float* b1_Wo = (const float*)d_in[6];
    const float* b1_bo = (const float*)d_in[7];
    const float* b1_gam = (const float*)d_in[8];
    const float* b1_lng = (const float*)d_in[9];
    const float* b1_lnb = (const float*)d_in[10];
    const float* b2_Wq = (const float*)d_in[11];
    const float* b2_bq = (const float*)d_in[12];
    const float* b2_Wv = (const float*)d_in[13];
    const float* b2_bv = (const float*)d_in[14];
    const float* b2_Wo = (const float*)d_in[15];
    const float* b2_bo = (const float*)d_in[16];
    const float* b2_gam = (const float*)d_in[17];
    const float* b2_lng = (const float*)d_in[18];
    const float* b2_lnb = (const float*)d_in[19];
    const float* b3_Wq = (const float*)d_in[20];
    const float* b3_bq = (const float*)d_in[21];
    const float* b3_Wk = (const float*)d_in[22];
    const float* b3_bk = (const float*)d_in[23];
    const float* b3_Wv = (const float*)d_in[24];
    const float* b3_bv = (const float*)d_in[25];
    const float* b3_Wo = (const float*)d_in[26];
    const float* b3_bo = (const float*)d_in[27];
    const float* b3_gam = (const float*)d_in[28];
    const float* b3_lng = (const float*)d_in[29];
    const float* b3_lnb = (const float*)d_in[30];
    const float* know  = (const float*)d_in[31];
    const float* lk_W  = (const float*)d_in[32];
    const float* lk_b  = (const float*)d_in[33];
    const float* lv_W  = (const float*)d_in[34];
    const float* lv_b  = (const float*)d_in[35];

    const size_t SLAB = (size_t)ROWS * DM;  // 1,048,576 floats = 4 MB
    const size_t USLAB = 2 * SLAB;          // split-bf16 buffer (hi+lo), ushorts
    float* A1 = (float*)d_ws;               // q1k1 f32; later k3
    float* A2 = A1 + SLAB;                  // q2k2 f32
    float* C1 = A2 + SLAB;                  // att1 out; later att3 out
    float* C2 = C1 + SLAB;                  // att2 out; later h3
    unsigned short* KS1 = (unsigned short*)(C2 + SLAB);  // later hq (f32)
    unsigned short* KS2 = KS1 + USLAB;                   // later ha (f32)
    unsigned short* VS1 = KS2 + USLAB;                   // later VS3
    unsigned short* VS2 = VS1 + USLAB;
    float* q3row = (float*)(VS2 + USLAB);   // 256
    float* key8  = q3row + DM;              // 8*256
    unsigned short* Wsp = (unsigned short*)(key8 + NH * DM);  // 9 x 256KB
    unsigned short* S3buf = Wsp + (size_t)9 * 131072;   // 16 x 2048 bf16
    float* C3buf = (float*)(S3buf + 16 * SEQ);          // 16 x 2048 f32
    float* hq = (float*)KS1;
    float* ha = (float*)KS2;
    float* k3 = A1;
    unsigned short* VS3 = VS1;
    float* O3 = C1;
    float* h3 = C2;

    auto WH = [&](int i) { return Wsp + (size_t)i * 131072; };
    // 0:b1_Wq 1:b1_Wv 2:b1_Wo 3:b2_Wq 4:b2_Wv 5:b2_Wo 6:b3_Wk 7:b3_Wv 8:b3_Wo

    dim3 blk(256);
    dim3 ablk(512);
    dim3 agrid2(SEQ / RT, 32);        // dual-set attention (128 x 32)
    dim3 agrid1(SEQ / RT, 16);        // single-set attention
    dim3 rgrid(ROWS);

    convert_w_kernel<<<dim3(64, 9), blk, 0, stream>>>(
        b1_Wq, b1_Wv, b1_Wo, b2_Wq, b2_Wv, b2_Wo, b3_Wk, b3_Wv, b3_Wo, Wsp);

    precompute_kernel<<<dim3(1), blk, 0, stream>>>(know, b3_Wq, b3_bq, lk_W, lk_b, q3row, key8);

    // ---- blocks 1+2 projections: q/k f32+rowsplit, v transposed-split ----
    gemm4_kernel<<<dim3(ROWS/16, 4), blk, 0, stream>>>(
        q_emb,  WH(0), b1_bq, A1,      KS1,     nullptr,
        q_emb,  WH(1), b1_bv, nullptr, nullptr, VS1,
        qa_emb, WH(3), b2_bq, A2,      KS2,     nullptr,
        qa_emb, WH(4), b2_bv, nullptr, nullptr, VS2);

    // ---- blocks 1+2 attention (one dual-set launch) ----
    attn_tile_kernel<<<agrid2, ablk, 0, stream>>>(
        A1, KS1, VS1, b1_gam, C1,
        A2, KS2, VS2, b2_gam, C2,
        nullptr, nullptr, 1, 0);

    // ---- output projections + residual + LN (fused) -> hq, ha ----
    gemm_ln2_kernel<<<dim3(ROWS/16, 2), blk, 0, stream>>>(
        C1, WH(2), b1_bo, q_emb,  b1_lng, b1_lnb, hq, 0,
        C2, WH(5), b2_bo, qa_emb, b2_lng, b2_lnb, ha, 0);

    // ---- block 3: k3 = hq@W3k (f32), v3 = ha@W3v (transposed split) ----
    gemm4_kernel<<<dim3(ROWS/16, 2), blk, 0, stream>>>(
        hq, WH(6), b3_bk, k3,      nullptr, nullptr,
        ha, WH(7), b3_bv, nullptr, nullptr, VS3,
        hq, WH(6), b3_bk, k3,      nullptr, nullptr,   // unused sets
        hq, WH(6), b3_bk, k3,      nullptr, nullptr);

    // ---- attn3 shared scores + scan, then attention ----
    score3_kernel<<<dim3(16), blk, 0, stream>>>(q3row, k3, S3buf, C3buf);

    attn_tile_kernel<<<agrid1, ablk, 0, stream>>>(
        q3row, nullptr, VS3, b3_gam, O3,
        q3row, nullptr, VS3, b3_gam, O3,
        S3buf, C3buf, 0, 1);

    // ---- y3 + know-residual + LN (fused) -> h3 ----
    gemm_ln2_kernel<<<dim3(ROWS/16, 1), blk, 0, stream>>>(
        O3, WH(8), b3_bo, know, b3_lng, b3_lnb, h3, 1,
        O3, WH(8), b3_bo, know, b3_lng, b3_lnb, h3, 1);

    readout_kernel<<<rgrid, blk, 0, stream>>>(h3, q_emb, key8, lv_W, lv_b,
                                              (float*)d_out);
}

// Round 26
// 544.863 us; speedup vs baseline: 1.1677x; 1.0939x over previous
//
#include <hip/hip_runtime.h>
#include <hip/hip_bf16.h>

#define DM 256
#define NH 8
#define DK 32
#define BSZ 2
#define SEQ 2048
#define ROWS (BSZ*SEQ)   // 4096
#define RT 16            // query rows per attention tile (full MFMA rows)
#define SRB 2312         // ushort row stride; swizzle phys = j + 8*(j>>6), max 2295

static __device__ __forceinline__ int sw8(int j) { return j + ((j >> 6) << 3); }

typedef __attribute__((ext_vector_type(8))) short short8;
typedef __attribute__((ext_vector_type(4))) float f32x4;

// f32 -> bf16 bits, round-to-nearest-even (validated r15)
static __device__ __forceinline__ unsigned short f2bf(float f) {
    unsigned u = __float_as_uint(f);
    return (unsigned short)((u + 0x7FFFu + ((u >> 16) & 1u)) >> 16);
}
static __device__ __forceinline__ float bf2f(unsigned short h) {
    return __uint_as_float(((unsigned)h) << 16);
}

#define MFMA_BF16 __builtin_amdgcn_mfma_f32_16x16x32_bf16
#define LOG2E 1.44269504088896340736f

// ---------- reduction helpers ----------
static __device__ __forceinline__ float waveRedSum(float v) {
    #pragma unroll
    for (int off = 32; off > 0; off >>= 1) v += __shfl_down(v, off, 64);
    return v;
}

// ---------- one-time: weights -> split-bf16, transposed [n][k] ----------
__global__ __launch_bounds__(256) void convert_w_kernel(
    const float* __restrict__ S0, const float* __restrict__ S1, const float* __restrict__ S2,
    const float* __restrict__ S3, const float* __restrict__ S4, const float* __restrict__ S5,
    const float* __restrict__ S6, const float* __restrict__ S7, const float* __restrict__ S8,
    unsigned short* __restrict__ dst)
{
    const float* W;
    int s = blockIdx.y;
    if (s == 0) W = S0; else if (s == 1) W = S1; else if (s == 2) W = S2;
    else if (s == 3) W = S3; else if (s == 4) W = S4; else if (s == 5) W = S5;
    else if (s == 6) W = S6; else if (s == 7) W = S7; else W = S8;
    unsigned short* H = dst + (size_t)s * 131072;
    unsigned short* L = H + 65536;

    int e = blockIdx.x * 1024 + threadIdx.x * 4;
    int k = e >> 8, n = e & 255;
    float4 w4 = *(const float4*)(W + e);
    float v[4] = {w4.x, w4.y, w4.z, w4.w};
    #pragma unroll
    for (int i = 0; i < 4; ++i) {
        unsigned short h = f2bf(v[i]);
        H[(size_t)(n + i) * 256 + k] = h;
        L[(size_t)(n + i) * 256 + k] = (unsigned short)f2bf(v[i] - bf2f(h));
    }
}

// ---------- batched MFMA GEMM (16x256/block, 4 sets) with optional ----------
// split-bf16 side outputs: KSo = [row][col] hi/lo; VSo = [col][row] hi only.
__global__ __launch_bounds__(256) void gemm4_kernel(
    const float* __restrict__ X0, const unsigned short* __restrict__ H0, const float* __restrict__ B0,
    float* __restrict__ Y0, unsigned short* __restrict__ K0o, unsigned short* __restrict__ V0o,
    const float* __restrict__ X1, const unsigned short* __restrict__ H1, const float* __restrict__ B1,
    float* __restrict__ Y1, unsigned short* __restrict__ K1o, unsigned short* __restrict__ V1o,
    const float* __restrict__ X2, const unsigned short* __restrict__ H2, const float* __restrict__ B2,
    float* __restrict__ Y2, unsigned short* __restrict__ K2o, unsigned short* __restrict__ V2o,
    const float* __restrict__ X3, const unsigned short* __restrict__ H3, const float* __restrict__ B3,
    float* __restrict__ Y3, unsigned short* __restrict__ K3o, unsigned short* __restrict__ V3o)
{
    const float *X, *Bias; const unsigned short* H; float* Yf;
    unsigned short *KSo, *VSo;
    int s = blockIdx.y;
    if (s == 0)      { X = X0; H = H0; Bias = B0; Yf = Y0; KSo = K0o; VSo = V0o; }
    else if (s == 1) { X = X1; H = H1; Bias = B1; Yf = Y1; KSo = K1o; VSo = V1o; }
    else if (s == 2) { X = X2; H = H2; Bias = B2; Yf = Y2; KSo = K2o; VSo = V2o; }
    else             { X = X3; H = H3; Bias = B3; Yf = Y3; KSo = K3o; VSo = V3o; }
    const unsigned short* L = H + 65536;

    __shared__ __align__(16) unsigned short XhL[16 * 264];
    __shared__ __align__(16) unsigned short XlL[16 * 264];
    int t = threadIdx.x;
    int r0 = blockIdx.x * 16;
    {   // stage X tile as split bf16
        int r = t >> 4, c0 = (t & 15) * 16;
        const float* xp = X + (size_t)(r0 + r) * DM + c0;
        #pragma unroll
        for (int i = 0; i < 16; i += 4) {
            float4 v4 = *(const float4*)(xp + i);
            float vv[4] = {v4.x, v4.y, v4.z, v4.w};
            #pragma unroll
            for (int j = 0; j < 4; ++j) {
                unsigned short h = f2bf(vv[j]);
                XhL[r * 264 + c0 + i + j] = h;
                XlL[r * 264 + c0 + i + j] = (unsigned short)f2bf(vv[j] - bf2f(h));
            }
        }
    }
    __syncthreads();
    int lane = t & 63, wv = t >> 6;
    int m = lane & 15, quad = lane >> 4;
    f32x4 aa[4];
    #pragma unroll
    for (int nt = 0; nt < 4; ++nt) { aa[nt][0]=0.f; aa[nt][1]=0.f; aa[nt][2]=0.f; aa[nt][3]=0.f; }
    #pragma unroll 1
    for (int kc = 0; kc < 8; ++kc) {
        int k0 = kc * 32;
        short8 Ah = *(const short8*)&XhL[m * 264 + k0 + quad * 8];
        short8 Al = *(const short8*)&XlL[m * 264 + k0 + quad * 8];
        size_t boff = (size_t)(wv * 64 + m) * 256 + k0 + quad * 8;
        #pragma unroll
        for (int nt = 0; nt < 4; ++nt) {
            short8 Bh = *(const short8*)(H + boff + nt * 16 * 256);
            short8 Bl = *(const short8*)(L + boff + nt * 16 * 256);
            aa[nt] = MFMA_BF16(Al, Bh, aa[nt], 0, 0, 0);
            aa[nt] = MFMA_BF16(Ah, Bl, aa[nt], 0, 0, 0);
            aa[nt] = MFMA_BF16(Ah, Bh, aa[nt], 0, 0, 0);
        }
    }
    // epilogue: D col = lane&15 (+16*nt +64*wv), row = quad*4+g
    int col0 = wv * 64 + m;
    #pragma unroll
    for (int nt = 0; nt < 4; ++nt) {
        int col = col0 + nt * 16;
        float bb = Bias[col];
        float yv[4];
        #pragma unroll
        for (int g = 0; g < 4; ++g) yv[g] = aa[nt][g] + bb;
        if (Yf) {
            #pragma unroll
            for (int g = 0; g < 4; ++g)
                Yf[(size_t)(r0 + quad * 4 + g) * DM + col] = yv[g];
        }
        if (KSo) {
            unsigned short* KH = KSo;
            unsigned short* KL = KSo + (size_t)ROWS * DM;
            #pragma unroll
            for (int g = 0; g < 4; ++g) {
                unsigned short hb = f2bf(yv[g]);
                KH[(size_t)(r0 + quad * 4 + g) * DM + col] = hb;
                KL[(size_t)(r0 + quad * 4 + g) * DM + col] =
                    (unsigned short)f2bf(yv[g] - bf2f(hb));
            }
        }
        if (VSo) {
            unsigned short* VH = VSo;
            ushort4 h4;
            h4.x = f2bf(yv[0]); h4.y = f2bf(yv[1]);
            h4.z = f2bf(yv[2]); h4.w = f2bf(yv[3]);
            *(ushort4*)&VH[(size_t)col * ROWS + r0 + quad * 4] = h4;
        }
    }
}

// ---------- MFMA GEMM + residual + LayerNorm fused (2 sets) ----------
__global__ __launch_bounds__(256) void gemm_ln2_kernel(
    const float* __restrict__ X0, const unsigned short* __restrict__ H0, const float* __restrict__ B0,
    const float* __restrict__ R0, const float* __restrict__ G0, const float* __restrict__ L0,
    float* __restrict__ Y0, int bc0,
    const float* __restrict__ X1, const unsigned short* __restrict__ H1, const float* __restrict__ B1,
    const float* __restrict__ R1, const float* __restrict__ G1, const float* __restrict__ L1,
    float* __restrict__ Y1, int bc1)
{
    const float *X, *Bias, *R, *G, *Lb; const unsigned short* H; float* Y; int bc;
    if (blockIdx.y == 0) { X=X0; H=H0; Bias=B0; R=R0; G=G0; Lb=L0; Y=Y0; bc=bc0; }
    else                 { X=X1; H=H1; Bias=B1; R=R1; G=G1; Lb=L1; Y=Y1; bc=bc1; }
    const unsigned short* L = H + 65536;

    __shared__ __align__(16) unsigned short XhL[16 * 264];
    __shared__ __align__(16) unsigned short XlL[16 * 264];
    __shared__ __align__(16) float yl[16 * 260];
    int t = threadIdx.x;
    int r0 = blockIdx.x * 16;
    {   int r = t >> 4, c0 = (t & 15) * 16;
        const float* xp = X + (size_t)(r0 + r) * DM + c0;
        #pragma unroll
        for (int i = 0; i < 16; i += 4) {
            float4 v4 = *(const float4*)(xp + i);
            float vv[4] = {v4.x, v4.y, v4.z, v4.w};
            #pragma unroll
            for (int j = 0; j < 4; ++j) {
                unsigned short h = f2bf(vv[j]);
                XhL[r * 264 + c0 + i + j] = h;
                XlL[r * 264 + c0 + i + j] = (unsigned short)f2bf(vv[j] - bf2f(h));
            }
        }
    }
    __syncthreads();
    int lane = t & 63, wv = t >> 6;
    int m = lane & 15, quad = lane >> 4;
    f32x4 aa[4];
    #pragma unroll
    for (int nt = 0; nt < 4; ++nt) { aa[nt][0]=0.f; aa[nt][1]=0.f; aa[nt][2]=0.f; aa[nt][3]=0.f; }
    #pragma unroll 1
    for (int kc = 0; kc < 8; ++kc) {
        int k0 = kc * 32;
        short8 Ah = *(const short8*)&XhL[m * 264 + k0 + quad * 8];
        short8 Al = *(const short8*)&XlL[m * 264 + k0 + quad * 8];
        size_t boff = (size_t)(wv * 64 + m) * 256 + k0 + quad * 8;
        #pragma unroll
        for (int nt = 0; nt < 4; ++nt) {
            short8 Bh = *(const short8*)(H + boff + nt * 16 * 256);
            short8 Bl = *(const short8*)(L + boff + nt * 16 * 256);
            aa[nt] = MFMA_BF16(Al, Bh, aa[nt], 0, 0, 0);
            aa[nt] = MFMA_BF16(Ah, Bl, aa[nt], 0, 0, 0);
            aa[nt] = MFMA_BF16(Ah, Bh, aa[nt], 0, 0, 0);
        }
    }
    {
        int col0 = wv * 64 + m;
        #pragma unroll
        for (int nt = 0; nt < 4; ++nt) {
            int col = col0 + nt * 16;
            float bb = Bias[col];
            #pragma unroll
            for (int g = 0; g < 4; ++g) {
                int row = quad * 4 + g;
                float res = bc ? R[col] : R[(size_t)(r0 + row) * DM + col];
                yl[row * 260 + col] = aa[nt][g] + bb + res;
            }
        }
    }
    __syncthreads();
    {
        int r = t >> 4, c0 = (t & 15) * 16;
        float vals[16];
        float part = 0.f;
        #pragma unroll
        for (int i = 0; i < 16; ++i) { vals[i] = yl[r * 260 + c0 + i]; part += vals[i]; }
        #pragma unroll
        for (int off = 8; off; off >>= 1) part += __shfl_xor(part, off, 16);
        float mean = part * (1.f / DM);
        float vp = 0.f;
        #pragma unroll
        for (int i = 0; i < 16; ++i) { float d = vals[i] - mean; vp += d * d; }
        #pragma unroll
        for (int off = 8; off; off >>= 1) vp += __shfl_xor(vp, off, 16);
        float rs = rsqrtf(vp * (1.f / DM) + 1e-5f);
        float* yp = Y + (size_t)(r0 + r) * DM + c0;
        #pragma unroll
        for (int i = 0; i < 16; i += 4) {
            float4 o;
            o.x = (vals[i+0] - mean) * rs * G[c0+i+0] + Lb[c0+i+0];
            o.y = (vals[i+1] - mean) * rs * G[c0+i+1] + Lb[c0+i+1];
            o.z = (vals[i+2] - mean) * rs * G[c0+i+2] + Lb[c0+i+2];
            o.w = (vals[i+3] - mean) * rs * G[c0+i+3] + Lb[c0+i+3];
            *(float4*)(yp + i) = o;
        }
    }
}

// ---------- attn3 shared scores + inclusive exp2 scan, one block per bh ----
__global__ __launch_bounds__(256) void score3_kernel(
    const float* __restrict__ q3row, const float* __restrict__ K3,
    unsigned short* __restrict__ S3, float* __restrict__ C3)
{
    __shared__ float wsum[4];
    int bh = blockIdx.x;           // b*8+h
    int b = bh >> 3, h = bh & 7;
    int t = threadIdx.x;
    int lane = t & 63, wv = t >> 6;
    const float scaleL2 = 0.17677669529663687f * LOG2E;
    float q[DK];
    #pragma unroll
    for (int d = 0; d < DK; ++d) q[d] = q3row[h * DK + d] * scaleL2;
    size_t kb = ((size_t)b * SEQ) * DM + h * DK;
    float einc[8];
    unsigned short sb[8];
    float run = 0.f;
    #pragma unroll 1
    for (int k = 0; k < 8; ++k) {
        int j = t * 8 + k;
        const float* kp = K3 + kb + (size_t)j * DM;
        float s = 0.f;
        #pragma unroll
        for (int d = 0; d < DK; ++d) s += q[d] * kp[d];
        unsigned short sb16 = f2bf(s);
        sb[k] = sb16;
        run += exp2f(bf2f(sb16));
        einc[k] = run;                 // inclusive within thread
    }
    // exclusive prefix of per-thread totals across 256 threads
    float x = run;
    #pragma unroll
    for (int off = 1; off < 64; off <<= 1) {
        float y = __shfl_up(x, off, 64);
        if (lane >= off) x += y;
    }
    if (lane == 63) wsum[wv] = x;
    __syncthreads();
    float woff = 0.f;
    for (int w = 0; w < wv; ++w) woff += wsum[w];
    float pre = woff + x - run;
    #pragma unroll
    for (int k = 0; k < 8; ++k) {
        int j = t * 8 + k;
        S3[(size_t)bh * SEQ + j] = sb[k];
        C3[(size_t)bh * SEQ + j] = pre + einc[k];
    }
}

// ---------- tiled attention with distance-decay bias ----------
// RT=16 + 512 threads. Phase 1: 2-MFMA QK (bf16 Q x split K — Ql·K term
// ~2^-9 rel, same order as bf16 score storage). Phase 5: P·Vh only (V-lo
// dropped, ~0.4% rel on O). attn3: precomputed shared scores + scan.
__global__ __launch_bounds__(512) void attn_tile_kernel(
    const float* __restrict__ Q0,
    const unsigned short* __restrict__ KS0, const unsigned short* __restrict__ VS0,
    const float* __restrict__ g0, float* __restrict__ O0,
    const float* __restrict__ Q1,
    const unsigned short* __restrict__ KS1, const unsigned short* __restrict__ VS1,
    const float* __restrict__ g1, float* __restrict__ O1,
    const unsigned short* __restrict__ S3g, const float* __restrict__ C3g,
    int peek, int qbcast)
{
    __shared__ __align__(16) unsigned short SB[RT * SRB];
    __shared__ float qs[RT][DK];
    __shared__ float l2inv_s[RT];
    __shared__ float rowsum[8 * RT];   // per-wave partial l (MFMA path)

    int y = blockIdx.y;
    int set = y >> 4, bh = y & 15;
    const float* Q = set ? Q1 : Q0;
    const unsigned short* KS = set ? KS1 : KS0;
    const unsigned short* VS = set ? VS1 : VS0;
    const float* gm = set ? g1 : g0;
    float* O = set ? O1 : O0;

    int b = bh >> 3, h = bh & 7;
    int i0 = ((int)gridDim.x - 1 - (int)blockIdx.x) * RT;   // largest-first
    int t = threadIdx.x;
    size_t base = ((size_t)b * SEQ) * DM + (size_t)h * DK;

    int njAll = peek ? (i0 + RT) : (i0 + RT - 1);  // >= 15 always
    int njPad32 = (njAll + 31) & ~31;
    int njPad128 = (njAll + 127) & ~127;           // pass-C extent
    const float scaleL2 = 0.17677669529663687f * LOG2E;   // 1/sqrt(32)*log2e

    if (!qbcast) {
        {   // load Q tile (512 threads = 16 rows x 32)
            int r = t >> 5, d = t & 31;
            qs[r][d] = Q[base + (size_t)(i0 + r) * DM + d];
        }
        __syncthreads();

        // ---- Phase 1: 2-MFMA scores + fused per-row exp2 partial sums.
        {
            int wave = t >> 6, lane = t & 63;
            int m = lane & 15, quad = lane >> 4;

            float av[8];
            {
                float4 qa = *(const float4*)&qs[m][8 * quad];
                float4 qb = *(const float4*)&qs[m][8 * quad + 4];
                av[0]=qa.x*scaleL2; av[1]=qa.y*scaleL2; av[2]=qa.z*scaleL2; av[3]=qa.w*scaleL2;
                av[4]=qb.x*scaleL2; av[5]=qb.y*scaleL2; av[6]=qb.z*scaleL2; av[7]=qb.w*scaleL2;
            }
            short8 Ah;
            #pragma unroll
            for (int i = 0; i < 8; ++i) Ah[i] = (short)f2bf(av[i]);

            const unsigned short* KH = KS;
            const unsigned short* KL = KS + (size_t)ROWS * DM;
            size_t rowb = (size_t)b * SEQ;
            int njr0 = i0 + quad * 4 + peek;      // nj of row quad*4
            float rp0 = 0.f, rp1 = 0.f, rp2 = 0.f, rp3 = 0.f;
            int nChunks = (njAll + 15) >> 4;
            #pragma unroll 1
            for (int c = wave; c < nChunks; c += 8) {
                int j0 = c << 4;
                size_t off = (rowb + j0 + m) * DM + h * DK + quad * 8;
                short8 Bh = *(const short8*)&KH[off];
                short8 Bl = *(const short8*)&KL[off];
                f32x4 acc = {0.f, 0.f, 0.f, 0.f};
                acc = MFMA_BF16(Ah, Bl, acc, 0, 0, 0);
                acc = MFMA_BF16(Ah, Bh, acc, 0, 0, 0);
                int jcol = j0 + m;
                int sj = sw8(jcol);
                #pragma unroll
                for (int g = 0; g < 4; ++g)
                    SB[(quad * 4 + g) * SRB + sj] = f2bf(acc[g]);
                rp0 += (jcol < njr0 + 0) ? exp2f(acc[0]) : 0.f;
                rp1 += (jcol < njr0 + 1) ? exp2f(acc[1]) : 0.f;
                rp2 += (jcol < njr0 + 2) ? exp2f(acc[2]) : 0.f;
                rp3 += (jcol < njr0 + 3) ? exp2f(acc[3]) : 0.f;
            }
            #pragma unroll
            for (int off = 1; off < 16; off <<= 1) {
                rp0 += __shfl_xor(rp0, off, 64);
                rp1 += __shfl_xor(rp1, off, 64);
                rp2 += __shfl_xor(rp2, off, 64);
                rp3 += __shfl_xor(rp3, off, 64);
            }
            if (m == 0) {
                rowsum[wave * RT + quad * 4 + 0] = rp0;
                rowsum[wave * RT + quad * 4 + 1] = rp1;
                rowsum[wave * RT + quad * 4 + 2] = rp2;
                rowsum[wave * RT + quad * 4 + 3] = rp3;
            }
        }
        __syncthreads();

        // ---- Tail fill: bf16 -inf into [nj_r, njPad128) per row ----
        {
            int r = t >> 5, c = t & 31;
            int i = i0 + r;
            int nj = peek ? (i + 1) : i;
            for (int j = nj + c; j < njPad128; j += 32)
                SB[r * SRB + sw8(j)] = 0xFF80u;   // bf16 -inf
        }
        __syncthreads();
    }

    // ---- Pass C ----
    if (qbcast) {
        int r = t >> 5, c = t & 31;
        int i = i0 + r;
        int nj = peek ? (i + 1) : i;
        unsigned short* Sr = SB + r * SRB;
        float gamma2 = -log1pf(__expf(gm[h])) * LOG2E;
        const unsigned short* s3p = S3g + (size_t)bh * SEQ;
        const float* c3p = C3g + (size_t)bh * SEQ;
        float linv = (nj > 0) ? 1.f / c3p[nj - 1] : 0.f;
        float l2 = 0.f;
        #pragma unroll 1
        for (int k = 0; 128 * k < njPad32; ++k) {
            int j4 = 128 * k + 4 * c;          // <= njPad128-4 <= 2044
            ushort4 su = *(const ushort4*)&s3p[j4];
            float4 C4 = *(const float4*)&c3p[j4];
            float pb = (float)(i - j4);
            float4 p;
            { float dist = sqrtf(fmaxf((1.f - C4.x * linv) * pb, 0.f));
              float eff = fmaxf(exp2f(dist * gamma2), 1e-5f);
              p.x = (j4 + 0 < nj) ? exp2f(bf2f(su.x) * eff) : 0.f; l2 += p.x; }
            { float dist = sqrtf(fmaxf((1.f - C4.y * linv) * (pb - 1.f), 0.f));
              float eff = fmaxf(exp2f(dist * gamma2), 1e-5f);
              p.y = (j4 + 1 < nj) ? exp2f(bf2f(su.y) * eff) : 0.f; l2 += p.y; }
            { float dist = sqrtf(fmaxf((1.f - C4.z * linv) * (pb - 2.f), 0.f));
              float eff = fmaxf(exp2f(dist * gamma2), 1e-5f);
              p.z = (j4 + 2 < nj) ? exp2f(bf2f(su.z) * eff) : 0.f; l2 += p.z; }
            { float dist = sqrtf(fmaxf((1.f - C4.w * linv) * (pb - 3.f), 0.f));
              float eff = fmaxf(exp2f(dist * gamma2), 1e-5f);
              p.w = (j4 + 3 < nj) ? exp2f(bf2f(su.w) * eff) : 0.f; l2 += p.w; }
            ushort4 pk;
            pk.x = f2bf(p.x); pk.y = f2bf(p.y); pk.z = f2bf(p.z); pk.w = f2bf(p.w);
            *(ushort4*)&Sr[sw8(j4)] = pk;
        }
        #pragma unroll
        for (int off = 16; off; off >>= 1) l2 += __shfl_xor(l2, off, 32);
        if (c == 0) l2inv_s[r] = (nj > 0) ? (1.f / l2) : 0.f;
    } else {
        int r = t >> 5, c = t & 31;
        int i = i0 + r;
        int nj = peek ? (i + 1) : i;
        unsigned short* Sr = SB + r * SRB;
        float gamma2 = -log1pf(__expf(gm[h])) * LOG2E;

        float l = 0.f;
        #pragma unroll
        for (int w = 0; w < 8; ++w) l += rowsum[w * RT + r];
        float linv = 1.f / l;

        float l2 = 0.f;
        float Bc = 0.f;
        #pragma unroll 1
        for (int k = 0; 128 * k < njPad32; ++k) {
            int j4 = 128 * k + 4 * c;
            uint2 u = *(const uint2*)&Sr[sw8(j4)];
            float4 s4;
            s4.x = bf2f((unsigned short)u.x);
            s4.y = bf2f((unsigned short)(u.x >> 16));
            s4.z = bf2f((unsigned short)u.y);
            s4.w = bf2f((unsigned short)(u.y >> 16));
            float e0 = exp2f(s4.x) * linv;
            float e1 = exp2f(s4.y) * linv;
            float e2 = exp2f(s4.z) * linv;
            float e3 = exp2f(s4.w) * linv;
            float sig = e0 + e1 + e2 + e3;
            float x = sig;
            #pragma unroll
            for (int off = 1; off < 32; off <<= 1) {
                float yv = __shfl_up(x, off, 32);
                if (c >= off) x += yv;
            }
            float tot = __shfl(x, 31, 32);
            float cum = Bc + (x - sig);
            Bc += tot;
            float pb = (float)(i - j4);
            float4 p;
            cum += e0;
            { float dist = sqrtf(fmaxf((1.f - cum) * pb, 0.f));
              float eff = fmaxf(exp2f(dist * gamma2), 1e-5f);
              p.x = exp2f(s4.x * eff); l2 += p.x; }
            cum += e1;
            { float dist = sqrtf(fmaxf((1.f - cum) * (pb - 1.f), 0.f));
              float eff = fmaxf(exp2f(dist * gamma2), 1e-5f);
              p.y = exp2f(s4.y * eff); l2 += p.y; }
            cum += e2;
            { float dist = sqrtf(fmaxf((1.f - cum) * (pb - 2.f), 0.f));
              float eff = fmaxf(exp2f(dist * gamma2), 1e-5f);
              p.z = exp2f(s4.z * eff); l2 += p.z; }
            cum += e3;
            { float dist = sqrtf(fmaxf((1.f - cum) * (pb - 3.f), 0.f));
              float eff = fmaxf(exp2f(dist * gamma2), 1e-5f);
              p.w = exp2f(s4.w * eff); l2 += p.w; }
            ushort4 pk;
            pk.x = f2bf(p.x); pk.y = f2bf(p.y); pk.z = f2bf(p.z); pk.w = f2bf(p.w);
            *(ushort4*)&Sr[sw8(j4)] = pk;
        }
        #pragma unroll
        for (int off = 16; off; off >>= 1) l2 += __shfl_xor(l2, off, 32);
        if (c == 0) l2inv_s[r] = (nj > 0) ? (1.f / l2) : 0.f;
    }
    __syncthreads();

    // ---- Phase 5 PV: MFMA, P bf16 in SB (A), V hi-only (B).
    {
        int wave = t >> 6, lane = t & 63;
        int n16 = lane & 15, quad = lane >> 4;
        const unsigned short* VH = VS;
        size_t vb0 = (size_t)(h * DK + n16) * ROWS + (size_t)b * SEQ;
        size_t vb1 = (size_t)(h * DK + 16 + n16) * ROWS + (size_t)b * SEQ;
        f32x4 oc0 = {0.f,0.f,0.f,0.f}, oc1 = {0.f,0.f,0.f,0.f};
        #pragma unroll 1
        for (int j0 = wave * 32; j0 < njPad32; j0 += 256) {
            short8 Ap = *(const short8*)&SB[n16 * SRB + sw8(j0 + quad * 8)];
            int jo = j0 + quad * 8;
            short8 Bh0 = *(const short8*)&VH[vb0 + jo];
            short8 Bh1 = *(const short8*)&VH[vb1 + jo];
            oc0 = MFMA_BF16(Ap, Bh0, oc0, 0, 0, 0);
            oc1 = MFMA_BF16(Ap, Bh1, oc1, 0, 0, 0);
        }
        __syncthreads();          // packed fully consumed -> reuse SB as f32
        float* FS = (float*)SB;
        {
            #pragma unroll
            for (int g = 0; g < 4; ++g) {
                int row = quad * 4 + g;
                FS[wave * 512 + row * 32 + n16] = oc0[g];
                FS[wave * 512 + row * 32 + 16 + n16] = oc1[g];
            }
        }
    }
    __syncthreads();
    {
        float* FS = (float*)SB;
        int r2 = t >> 5, d = t & 31;
        float sum = 0.f;
        #pragma unroll
        for (int w = 0; w < 8; ++w)
            sum += FS[w * 512 + r2 * 32 + d];
        int ii = i0 + r2;
        O[base + (size_t)ii * DM + d] = sum * l2inv_s[r2];
    }
}

// ---------- small precompute: q3row = know@W3q+b3q; key8 = sigmoid heads ---
__global__ __launch_bounds__(256) void precompute_kernel(
    const float* __restrict__ know,
    const float* __restrict__ W3q, const float* __restrict__ b3q,
    const float* __restrict__ lkW, const float* __restrict__ lkb,
    float* __restrict__ q3row, float* __restrict__ key8)
{
    __shared__ float kn[DM];
    int t = threadIdx.x;
    kn[t] = know[t];
    __syncthreads();
    float acc = b3q[t];
    for (int c = 0; c < DM; ++c) acc += kn[c] * W3q[(size_t)c * DM + t];
    q3row[t] = acc;
    float bk = lkb[t];
    for (int h = 0; h < NH; ++h) {
        float a = bk;
        #pragma unroll
        for (int c = 0; c < DK; ++c) a += kn[h * DK + c] * lkW[(size_t)c * DM + t];
        key8[(size_t)h * DM + t] = 1.f / (1.f + __expf(-a));
    }
}

// ---------- final readout (f32 output), single-barrier beta reduction ------
__global__ __launch_bounds__(256) void readout_kernel(
    const float* __restrict__ h3, const float* __restrict__ qe,
    const float* __restrict__ key8,
    const float* __restrict__ lvW, const float* __restrict__ lvb,
    float* __restrict__ out)
{
    __shared__ float hrow[DM], qrow[DM];
    __shared__ float red8[4][NH];
    int n = blockIdx.x, t = threadIdx.x;
    int lane = t & 63, wid = t >> 6;
    hrow[t] = h3[(size_t)n * DM + t];
    qrow[t] = qe[(size_t)n * DM + t];
    __syncthreads();
    float ph[NH];
    #pragma unroll
    for (int h = 0; h < NH; ++h) {
        float v = key8[(size_t)h * DM + t] * qrow[t];
        v = waveRedSum(v);
        ph[h] = v;
    }
    if (lane == 0) {
        #pragma unroll
        for (int h = 0; h < NH; ++h) red8[wid][h] = ph[h];
    }
    __syncthreads();
    float beta[NH];
    #pragma unroll
    for (int h = 0; h < NH; ++h)
        beta[h] = red8[0][h] + red8[1][h] + red8[2][h] + red8[3][h];
    float bv = lvb[t];
    float vh[NH];
    for (int h = 0; h < NH; ++h) {
        float a = bv;
        #pragma unroll
        for (int c = 0; c < DK; ++c) a += hrow[h * DK + c] * lvW[(size_t)c * DM + t];
        vh[h] = 1.f / (1.f + __expf(-a));
    }
    float mb = beta[0];
    #pragma unroll
    for (int h = 1; h < NH; ++h) mb = fmaxf(mb, beta[h]);
    float se = 0.f, eh[NH];
    #pragma unroll
    for (int h = 0; h < NH; ++h) { eh[h] = __expf(beta[h] - mb); se += eh[h]; }
    float sinv = 1.f / se;
    float o = 0.f;
    #pragma unroll
    for (int h = 0; h < NH; ++h) o += eh[h] * sinv * vh[h];
    out[(size_t)n * DM + t] = o;
}

extern "C" void kernel_launch(void* const* d_in, const int* in_sizes, int n_in,
                              void* d_out, int out_size, void* d_ws, size_t ws_size,
                              hipStream_t stream) {
    (void)in_sizes; (void)n_in; (void)out_size; (void)ws_size;
    const float* q_emb  = (const float*)d_in[0];
    const float* qa_emb = (const float*)d_in[1];
    const float* b1_Wq = (const float*)d_in[2];
    const float* b1_bq = (const float*)d_in[3];
    const float* b1_Wv = (const float*)d_in[4];
    const float* b1_bv = (const float*)d_in[5];
    const float* b1_Wo = (const float*)d_in[6];
    const float* b1_bo = (const float*)d_in[7];
    const float* b1_gam = (const float*)d_in[8];
    const float* b1_lng = (const float*)d_in[9];
    const float* b1_lnb = (const float*)d_in[10];
    const float* b2_Wq = (const float*)d_in[11];
    const float* b2_bq = (const float*)d_in[12];
    const float* b2_Wv = (const float*)d_in[13];
    const float* b2_bv = (const float*)d_in[14];
    const float* b2_Wo = (const float*)d_in[15];
    const float* b2_bo = (const float*)d_in[16];
    const float* b2_gam = (const float*)d_in[17];
    const float* b2_lng = (const float*)d_in[18];
    const float* b2_lnb = (const float*)d_in[19];
    const float* b3_Wq = (const float*)d_in[20];
    const float* b3_bq = (const float*)d_in[21];
    const float* b3_Wk = (const float*)d_in[22];
    const float* b3_bk = (const float*)d_in[23];
    const float* b3_Wv = (const float*)d_in[24];
    const float* b3_bv = (const float*)d_in[25];
    const float* b3_Wo = (const float*)d_in[26];
    const float* b3_bo = (const float*)d_in[27];
    const float* b3_gam = (const float*)d_in[28];
    const float* b3_lng = (const float*)d_in[29];
    const float* b3_lnb = (const float*)d_in[30];
    const float* know  = (const float*)d_in[31];
    const float* lk_W  = (const float*)d_in[32];
    const float* lk_b  = (const float*)d_in[33];
    const float* lv_W  = (const float*)d_in[34];
    const float* lv_b  = (const float*)d_in[35];

    const size_t SLAB = (size_t)ROWS * DM;  // 1,048,576 floats = 4 MB
    const size_t USLAB = 2 * SLAB;          // split-bf16 buffer (hi+lo), ushorts
    float* A1 = (float*)d_ws;               // q1k1 f32; later k3
    float* A2 = A1 + SLAB;                  // q2k2 f32
    float* C1 = A2 + SLAB;                  // att1 out; later att3 out
    float* C2 = C1 + SLAB;                  // att2 out; later h3
    unsigned short* KS1 = (unsigned short*)(C2 + SLAB);  // later hq (f32)
    unsigned short* KS2 = KS1 + USLAB;                   // later ha (f32)
    unsigned short* VS1 = KS2 + USLAB;                   // later VS3 (hi only)
    unsigned short* VS2 = VS1 + USLAB;
    float* q3row = (float*)(VS2 + USLAB);   // 256
    float* key8  = q3row + DM;              // 8*256
    unsigned short* Wsp = (unsigned short*)(key8 + NH * DM);  // 9 x 256KB
    unsigned short* S3buf = Wsp + (size_t)9 * 131072;   // 16 x 2048 bf16
    float* C3buf = (float*)(S3buf + 16 * SEQ);          // 16 x 2048 f32
    float* hq = (float*)KS1;
    float* ha = (float*)KS2;
    float* k3 = A1;
    unsigned short* VS3 = VS1;
    float* O3 = C1;
    float* h3 = C2;

    auto WH = [&](int i) { return Wsp + (size_t)i * 131072; };
    // 0:b1_Wq 1:b1_Wv 2:b1_Wo 3:b2_Wq 4:b2_Wv 5:b2_Wo 6:b3_Wk 7:b3_Wv 8:b3_Wo

    dim3 blk(256);
    dim3 ablk(512);
    dim3 agrid2(SEQ / RT, 32);        // dual-set attention (128 x 32)
    dim3 agrid1(SEQ / RT, 16);        // single-set attention
    dim3 rgrid(ROWS);

    convert_w_kernel<<<dim3(64, 9), blk, 0, stream>>>(
        b1_Wq, b1_Wv, b1_Wo, b2_Wq, b2_Wv, b2_Wo, b3_Wk, b3_Wv, b3_Wo, Wsp);

    precompute_kernel<<<dim3(1), blk, 0, stream>>>(know, b3_Wq, b3_bq, lk_W, lk_b, q3row, key8);

    // ---- blocks 1+2 projections: q/k f32+rowsplit, v transposed hi-bf16 ----
    gemm4_kernel<<<dim3(ROWS/16, 4), blk, 0, stream>>>(
        q_emb,  WH(0), b1_bq, A1,      KS1,     nullptr,
        q_emb,  WH(1), b1_bv, nullptr, nullptr, VS1,
        qa_emb, WH(3), b2_bq, A2,      KS2,     nullptr,
        qa_emb, WH(4), b2_bv, nullptr, nullptr, VS2);

    // ---- blocks 1+2 attention (one dual-set launch) ----
    attn_tile_kernel<<<agrid2, ablk, 0, stream>>>(
        A1, KS1, VS1, b1_gam, C1,
        A2, KS2, VS2, b2_gam, C2,
        nullptr, nullptr, 1, 0);

    // ---- output projections + residual + LN (fused) -> hq, ha ----
    gemm_ln2_kernel<<<dim3(ROWS/16, 2), blk, 0, stream>>>(
        C1, WH(2), b1_bo, q_emb,  b1_lng, b1_lnb, hq, 0,
        C2, WH(5), b2_bo, qa_emb, b2_lng, b2_lnb, ha, 0);

    // ---- block 3: k3 = hq@W3k (f32), v3 = ha@W3v (transposed hi-bf16) ----
    gemm4_kernel<<<dim3(ROWS/16, 2), blk, 0, stream>>>(
        hq, WH(6), b3_bk, k3,      nullptr, nullptr,
        ha, WH(7), b3_bv, nullptr, nullptr, VS3,
        hq, WH(6), b3_bk, k3,      nullptr, nullptr,   // unused sets
        hq, WH(6), b3_bk, k3,      nullptr, nullptr);

    // ---- attn3 shared scores + scan, then attention ----
    score3_kernel<<<dim3(16), blk, 0, stream>>>(q3row, k3, S3buf, C3buf);

    attn_tile_kernel<<<agrid1, ablk, 0, stream>>>(
        q3row, nullptr, VS3, b3_gam, O3,
        q3row, nullptr, VS3, b3_gam, O3,
        S3buf, C3buf, 0, 1);

    // ---- y3 + know-residual + LN (fused) -> h3 ----
    gemm_ln2_kernel<<<dim3(ROWS/16, 1), blk, 0, stream>>>(
        O3, WH(8), b3_bo, know, b3_lng, b3_lnb, h3, 1,
        O3, WH(8), b3_bo, know, b3_lng, b3_lnb, h3, 1);

    readout_kernel<<<rgrid, blk, 0, stream>>>(h3, q_emb, key8, lv_W, lv_b,
                                              (float*)d_out);
}